// Round 23
// baseline (293.702 us; speedup 1.0000x reference)
//
#include <hip/hip_runtime.h>
#include <hip/hip_fp16.h>
#include <math.h>

// Problem constants (fixed by the reference)
constexpr int Nn  = 40000;
constexpr int Ee  = 640000;
constexpr int Fd  = 128;
constexpr int Hid = 256;
constexpr int Cc  = 20;
constexpr float GEN_EPS = 1e-7f;
constexpr float LN_EPS  = 1e-5f;

using bfrag = __attribute__((ext_vector_type(8))) short;   // 8 bf16 (4 VGPR)
using f32x4 = __attribute__((ext_vector_type(4))) float;   // 4 fp32 acc
typedef __attribute__((ext_vector_type(4))) unsigned short us4;

__device__ __forceinline__ unsigned short f2bf(float f) {
  unsigned u = __float_as_uint(f);
  u += 0x7FFF + ((u >> 16) & 1);          // RNE
  return (unsigned short)(u >> 16);
}

// ---------------- CSR build ----------------
__global__ void zero_int_k(int* __restrict__ p, int n) {
  int i = blockIdx.x * 256 + threadIdx.x;
  if (i < n) p[i] = 0;
}

// counts + per-edge rank (stable position within its dst segment)
__global__ void count_k(const int* __restrict__ dst, int* __restrict__ cnt,
                        int* __restrict__ rank) {
  int e = blockIdx.x * 256 + threadIdx.x;
  if (e < Ee) rank[e] = atomicAdd(&cnt[dst[e]], 1);
}

__device__ __forceinline__ int block_incl_scan256(int v) {
  int t = threadIdx.x, lane = t & 63, wid = t >> 6;
  int x = v;
  #pragma unroll
  for (int off = 1; off < 64; off <<= 1) {
    int y = __shfl_up(x, off);
    if (lane >= off) x += y;
  }
  __shared__ int wsum[4];
  if (lane == 63) wsum[wid] = x;
  __syncthreads();
  int add = 0;
  #pragma unroll
  for (int w = 0; w < 4; ++w) if (w < wid) add += wsum[w];
  return x + add;
}

__global__ __launch_bounds__(256) void blocksum_k(const int* __restrict__ cnt,
                                                  int* __restrict__ bsum, int n) {
  int i = blockIdx.x * 256 + threadIdx.x;
  int v = (i < n) ? cnt[i] : 0;
  int lane = threadIdx.x & 63, wid = threadIdx.x >> 6;
  #pragma unroll
  for (int m = 32; m >= 1; m >>= 1) v += __shfl_xor(v, m);
  __shared__ int s4[4];
  if (lane == 0) s4[wid] = v;
  __syncthreads();
  if (threadIdx.x == 0) bsum[blockIdx.x] = s4[0] + s4[1] + s4[2] + s4[3];
}

__global__ __launch_bounds__(256) void scanbsum_k(int* __restrict__ bsum, int nb) {
  int t = threadIdx.x;
  int v = (t < nb) ? bsum[t] : 0;
  int incl = block_incl_scan256(v);
  if (t < nb) bsum[t] = incl - v;   // exclusive
}

__global__ __launch_bounds__(256) void scanfinal_k(const int* __restrict__ cnt,
                                                   const int* __restrict__ bsum,
                                                   int* __restrict__ row_ptr, int n) {
  int b = blockIdx.x, t = threadIdx.x;
  int i = b * 256 + t;
  int v = (i < n) ? cnt[i] : 0;
  int incl = block_incl_scan256(v);
  if (i < n) row_ptr[i + 1] = bsum[b] + incl;
  if (b == 0 && t == 0) row_ptr[0] = 0;
}

// atomic-free scatter: position = row_ptr[dst] + precomputed rank
__global__ void scatter_k(const int* __restrict__ src, const int* __restrict__ dst,
                          const float* __restrict__ eattr,
                          const int* __restrict__ row_ptr, const int* __restrict__ rank,
                          uint2* __restrict__ cole) {
  int e = blockIdx.x * 256 + threadIdx.x;
  if (e >= Ee) return;
  int d = dst[e];
  int p = row_ptr[d] + rank[e];
  cole[p] = make_uint2((unsigned)src[e], __float_as_uint(eattr[e]));
}

// deg (incl self loop) -> dis = rsqrt(deg)
__global__ void deg_dis_k(const int* __restrict__ row_ptr, const uint2* __restrict__ cole,
                          float* __restrict__ dis) {
  int i = blockIdx.x * 256 + threadIdx.x;
  if (i >= Nn) return;
  int b = row_ptr[i], e = row_ptr[i + 1];
  float s = 1.f;                         // self-loop weight
  for (int j = b; j < e; ++j) s += __uint_as_float(cole[j].y);
  dis[i] = (s > 0.f) ? rsqrtf(s) : 0.f;
}

// ---------------- weight prep: fp32 -> MFMA-fragment-ordered bf16 (hi plane only) ----------------
__global__ void prep_w_k(const float* __restrict__ w1, const float* __restrict__ w2,
                         unsigned short* __restrict__ w1h, unsigned short* __restrict__ w2h) {
  int i = blockIdx.x * 256 + threadIdx.x;
  constexpr int TOT = 3 * Fd * Hid;   // 98304
  if (i >= TOT) return;
  int j = i & 7, l = (i >> 3) & 63, tk = (i >> 9) & 63, layer = i >> 15;
  int k_lo = (l >> 4) * 4 + (j & 3) + 16 * (j >> 2);
  {
    int kc = tk >> 4, tt = tk & 15;          // w1: K=128 (kc<4), N=256 (tt<16)
    int k = kc * 32 + k_lo, c = tt * 16 + (l & 15);
    w1h[i] = f2bf(w1[((size_t)layer * Fd + k) * Hid + c]);
  }
  {
    int kc = tk >> 3, tt = tk & 7;           // w2: K=256 (kc<8), N=128 (tt<8)
    int k = kc * 32 + k_lo, c = tt * 16 + (l & 15);
    w2h[i] = f2bf(w2[((size_t)layer * Hid + k) * Fd + c]);
  }
}

// ---------------- fused embedding gather + layer-0 LN/ReLU ----------------
__global__ __launch_bounds__(256) void embed_ln_k(const int* __restrict__ ids,
                                                  const float* __restrict__ emb,
                                                  const float* __restrict__ g,
                                                  const float* __restrict__ b,
                                                  float* __restrict__ h,
                                                  __half* __restrict__ xnh) {
  int node = blockIdx.x * 4 + (threadIdx.x >> 6);
  int lane = threadIdx.x & 63;
  float2 v = *(const float2*)(emb + (size_t)ids[node] * Fd + lane * 2);
  *(float2*)(h + (size_t)node * Fd + lane * 2) = v;
  float s = v.x + v.y;
  #pragma unroll
  for (int m = 32; m >= 1; m >>= 1) s += __shfl_xor(s, m);
  float mu = s * (1.f / 128.f);
  float d0 = v.x - mu, d1 = v.y - mu;
  float q = d0 * d0 + d1 * d1;
  #pragma unroll
  for (int m = 32; m >= 1; m >>= 1) q += __shfl_xor(q, m);
  float rs = rsqrtf(q * (1.f / 128.f) + LN_EPS);
  float2 gg = *(const float2*)(g + lane * 2);
  float2 bb = *(const float2*)(b + lane * 2);
  float ox = fmaxf(d0 * rs * gg.x + bb.x, 0.f);
  float oy = fmaxf(d1 * rs * gg.y + bb.y, 0.f);
  *(__half2*)(xnh + (size_t)node * Fd + lane * 2) = __floats2half2_rn(ox, oy);
}

// ---------------- GENConv aggregation: 4 nodes/wave, 8 features/lane -> bf16 h2 ----------------
__global__ __launch_bounds__(256) void gen_agg_k(const __half* __restrict__ xnh,
                                                 const int* __restrict__ row_ptr,
                                                 const uint2* __restrict__ cole,
                                                 const float* __restrict__ t_ptr,
                                                 unsigned short* __restrict__ h2b) {
  int wid = blockIdx.x * 4 + (threadIdx.x >> 6);
  int lane = threadIdx.x & 63;
  int sub = lane >> 4;
  int node = wid * 4 + sub;
  int f0 = (lane & 15) * 8;
  float t = t_ptr[0];
  int beg = row_ptr[node], end = row_ptr[node + 1];
  const __half* xb = xnh + f0;
  float se[8], sm[8];
  #pragma unroll
  for (int i = 0; i < 8; ++i) { se[i] = 0.f; sm[i] = 0.f; }

  for (int j = beg; j < end; j += 8) {
    int idx[8];
    #pragma unroll
    for (int k = 0; k < 8; ++k) idx[k] = (j + k < end) ? (int)cole[j + k].x : -1;
    uint4 hv[8];
    #pragma unroll
    for (int k = 0; k < 8; ++k)
      if (idx[k] >= 0) hv[k] = *(const uint4*)(xb + (size_t)idx[k] * Fd);
    #pragma unroll
    for (int k = 0; k < 8; ++k) {
      if (idx[k] >= 0) {
        const __half2* hp = (const __half2*)&hv[k];
        #pragma unroll
        for (int q = 0; q < 4; ++q) {
          float2 v = __half22float2(hp[q]);
          float m0 = v.x + GEN_EPS, m1 = v.y + GEN_EPS;
          float e0 = __expf(t * m0), e1 = __expf(t * m1);
          se[2 * q]     += e0;  se[2 * q + 1] += e1;
          sm[2 * q]      = fmaf(m0, e0, sm[2 * q]);
          sm[2 * q + 1]  = fmaf(m1, e1, sm[2 * q + 1]);
        }
      }
    }
  }

  // self/residual term from fp16 row; output bf16 (one 16B store)
  uint4 sv = *(const uint4*)(xb + (size_t)node * Fd);
  const __half2* sp2 = (const __half2*)&sv;
  unsigned short ob[8];
  #pragma unroll
  for (int q = 0; q < 4; ++q) {
    float2 sf = __half22float2(sp2[q]);
    ob[2 * q]     = f2bf(sf.x + sm[2 * q]     / (se[2 * q]     + 1e-16f));
    ob[2 * q + 1] = f2bf(sf.y + sm[2 * q + 1] / (se[2 * q + 1] + 1e-16f));
  }
  *(uint4*)(h2b + (size_t)node * Fd + f0) = *(uint4*)ob;
}

// ======== fused MLP core (phase 1: z = relu(LN(h2@W1+b1)) in LDS; phase 2: z@W2) ========
__device__ __forceinline__ void mlp_core(const unsigned short* __restrict__ Az,
                                         const unsigned short* __restrict__ W1h,
                                         const float* __restrict__ b1,
                                         const float* __restrict__ g1,
                                         const float* __restrict__ bl1,
                                         const unsigned short* __restrict__ W2h,
                                         int r0,
                                         unsigned short (*Ab)[136],
                                         unsigned short (*Zl)[264],
                                         float (*sred)[32][2],
                                         f32x4* acc2) {
  const int t = threadIdx.x;
  const int w = t >> 6, l = t & 63;
  const int rg = w & 1, cg = w >> 1;
  const int g4 = l >> 4, cl = l & 15;

  // stage h2 (K=128 bf16) fragment-permuted
  {
    int row = t >> 3;
    int base = (t & 7) * 16;
    const unsigned short* sp = Az + (size_t)(r0 + row) * Fd + base;
    #pragma unroll
    for (int hb = 0; hb < 2; ++hb) {
      int kk0 = base + hb * 8;
      uint4 a = *(const uint4*)(sp + hb * 8);
      int chunk = kk0 >> 5, ww = kk0 & 31;
      int d = chunk * 32 + 8 * ((ww & 15) >> 2) + 4 * (ww >> 4);
      us4 v0 = {(unsigned short)a.x, (unsigned short)(a.x >> 16),
                (unsigned short)a.y, (unsigned short)(a.y >> 16)};
      us4 v1 = {(unsigned short)a.z, (unsigned short)(a.z >> 16),
                (unsigned short)a.w, (unsigned short)(a.w >> 16)};
      *(us4*)&Ab[row][d] = v0;
      *(us4*)&Ab[row][d + 8] = v1;
    }
  }
  __syncthreads();

  // phase 1 MFMA: 8 col tiles of this cg's 128 cols
  f32x4 acc[8];
  #pragma unroll
  for (int i = 0; i < 8; ++i) acc[i] = (f32x4){0.f, 0.f, 0.f, 0.f};
  for (int kc = 0; kc < 4; ++kc) {
    bfrag ab = *(const bfrag*)&Ab[16 * rg + cl][kc * 32 + g4 * 8];
    const unsigned short* bh = W1h + ((size_t)(kc * 16 + cg * 8) * 64 + l) * 8;
    #pragma unroll
    for (int tt = 0; tt < 8; ++tt) {
      bfrag vbh = *(const bfrag*)(bh + tt * 512);
      acc[tt] = __builtin_amdgcn_mfma_f32_16x16x32_bf16(ab, vbh, acc[tt], 0, 0, 0);
    }
  }

  // LN pass 1: +bias, per-row partial (s,q) over this wave's 128 cols
  float bcol[8], gcol[8], blc[8];
  #pragma unroll
  for (int tt = 0; tt < 8; ++tt) {
    int c = cg * 128 + 16 * tt + cl;
    bcol[tt] = b1[c]; gcol[tt] = g1[c]; blc[tt] = bl1[c];
  }
  #pragma unroll
  for (int j = 0; j < 4; ++j) {
    float s = 0.f, q = 0.f;
    #pragma unroll
    for (int tt = 0; tt < 8; ++tt) {
      float x = acc[tt][j] + bcol[tt];
      acc[tt][j] = x;
      s += x;
      q = fmaf(x, x, q);
    }
    #pragma unroll
    for (int m = 8; m >= 1; m >>= 1) { s += __shfl_xor(s, m); q += __shfl_xor(q, m); }
    if (cl == 0) {
      int rl = 16 * rg + 4 * g4 + j;
      sred[cg][rl][0] = s;
      sred[cg][rl][1] = q;
    }
  }
  __syncthreads();
  // LN pass 2: combine, normalize, relu, write z to LDS fragment-permuted
  #pragma unroll
  for (int j = 0; j < 4; ++j) {
    int rl = 16 * rg + 4 * g4 + j;
    float s = sred[0][rl][0] + sred[1][rl][0];
    float q = sred[0][rl][1] + sred[1][rl][1];
    float mu = s * (1.f / 256.f);
    float rs = rsqrtf(q * (1.f / 256.f) - mu * mu + LN_EPS);
    #pragma unroll
    for (int tt = 0; tt < 8; ++tt) {
      float z = fmaxf((acc[tt][j] - mu) * rs * gcol[tt] + blc[tt], 0.f);
      int d = (cl & 3) + 8 * (cl >> 2) + 4 * (tt & 1) + 32 * ((tt >> 1) + 4 * cg);
      Zl[rl][d] = f2bf(z);
    }
  }
  __syncthreads();                      // z tile complete (also fences sred reuse)

  // phase 2 MFMA: 4 col tiles of this cg's 64 cols, K=256 from Zl
  #pragma unroll
  for (int i = 0; i < 4; ++i) acc2[i] = (f32x4){0.f, 0.f, 0.f, 0.f};
  for (int kf = 0; kf < 8; ++kf) {
    bfrag ab = *(const bfrag*)&Zl[16 * rg + cl][kf * 32 + g4 * 8];
    const unsigned short* bh = W2h + ((size_t)(kf * 8 + cg * 4) * 64 + l) * 8;
    #pragma unroll
    for (int tt = 0; tt < 4; ++tt) {
      bfrag vbh = *(const bfrag*)(bh + tt * 512);
      acc2[tt] = __builtin_amdgcn_mfma_f32_16x16x32_bf16(ab, vbh, acc2[tt], 0, 0, 0);
    }
  }
}

// ---------------- fused MLP, layers 0/1: H += out + b2; XNh = relu(LN(H)) ----------------
__global__ __launch_bounds__(256) void mlp0_k(const unsigned short* __restrict__ Az,
                                              const unsigned short* __restrict__ W1h,
                                              const float* __restrict__ b1,
                                              const float* __restrict__ g1,
                                              const float* __restrict__ bl1,
                                              const unsigned short* __restrict__ W2h,
                                              const float* __restrict__ b2,
                                              float* __restrict__ H,
                                              const float* __restrict__ gN,
                                              const float* __restrict__ blN,
                                              __half* __restrict__ XNh) {
  __shared__ unsigned short Ab[32][136];
  __shared__ unsigned short Zl[32][264];
  __shared__ float sred[2][32][2];
  const int t = threadIdx.x;
  const int w = t >> 6, l = t & 63;
  const int rg = w & 1, cg = w >> 1;
  const int g4 = l >> 4, cl = l & 15;
  const int r0 = blockIdx.x * 32;

  f32x4 acc2[4];
  mlp_core(Az, W1h, b1, g1, bl1, W2h, r0, Ab, Zl, sred, acc2);

  float bcol[4], gcol[4], blc[4];
  #pragma unroll
  for (int tt = 0; tt < 4; ++tt) {
    int c = cg * 64 + 16 * tt + cl;
    bcol[tt] = b2[c];
    gcol[tt] = gN[c]; blc[tt] = blN[c];
  }
  // pass 1: residual + H write + per-row partials over 64 cols
  #pragma unroll
  for (int j = 0; j < 4; ++j) {
    int row = r0 + 16 * rg + 4 * g4 + j;
    float s = 0.f, q = 0.f;
    #pragma unroll
    for (int tt = 0; tt < 4; ++tt) {
      size_t off = (size_t)row * Fd + cg * 64 + 16 * tt + cl;
      float hv = H[off] + acc2[tt][j] + bcol[tt];
      H[off] = hv;
      acc2[tt][j] = hv;
      s += hv;
      q = fmaf(hv, hv, q);
    }
    #pragma unroll
    for (int m = 8; m >= 1; m >>= 1) { s += __shfl_xor(s, m); q += __shfl_xor(q, m); }
    if (cl == 0) {
      int rl = 16 * rg + 4 * g4 + j;
      sred[cg][rl][0] = s;
      sred[cg][rl][1] = q;
    }
  }
  __syncthreads();
  // pass 2: combine, normalize, write fp16
  #pragma unroll
  for (int j = 0; j < 4; ++j) {
    int rl = 16 * rg + 4 * g4 + j;
    float s = sred[0][rl][0] + sred[1][rl][0];
    float q = sred[0][rl][1] + sred[1][rl][1];
    float mu = s * (1.f / 128.f);
    float rs = rsqrtf(q * (1.f / 128.f) - mu * mu + LN_EPS);
    int row = r0 + rl;
    #pragma unroll
    for (int tt = 0; tt < 4; ++tt) {
      float z = fmaxf((acc2[tt][j] - mu) * rs * gcol[tt] + blc[tt], 0.f);
      XNh[(size_t)row * Fd + cg * 64 + 16 * tt + cl] = __float2half_rn(z);
    }
  }
}

// ---------------- fused MLP, last layer: hfin = fp16(H + out + b2) (no LN) ----------------
__global__ __launch_bounds__(256) void mlp2_k(const unsigned short* __restrict__ Az,
                                              const unsigned short* __restrict__ W1h,
                                              const float* __restrict__ b1,
                                              const float* __restrict__ g1,
                                              const float* __restrict__ bl1,
                                              const unsigned short* __restrict__ W2h,
                                              const float* __restrict__ b2,
                                              const float* __restrict__ H,
                                              __half* __restrict__ hfin) {
  __shared__ unsigned short Ab[32][136];
  __shared__ unsigned short Zl[32][264];
  __shared__ float sred[2][32][2];
  const int t = threadIdx.x;
  const int w = t >> 6, l = t & 63;
  const int rg = w & 1, cg = w >> 1;
  const int g4 = l >> 4, cl = l & 15;
  const int r0 = blockIdx.x * 32;

  f32x4 acc2[4];
  mlp_core(Az, W1h, b1, g1, bl1, W2h, r0, Ab, Zl, sred, acc2);

  float bcol[4];
  #pragma unroll
  for (int tt = 0; tt < 4; ++tt) bcol[tt] = b2[cg * 64 + 16 * tt + cl];
  #pragma unroll
  for (int j = 0; j < 4; ++j) {
    int row = r0 + 16 * rg + 4 * g4 + j;
    #pragma unroll
    for (int tt = 0; tt < 4; ++tt) {
      size_t off = (size_t)row * Fd + cg * 64 + 16 * tt + cl;
      hfin[off] = __float2half_rn(H[off] + acc2[tt][j] + bcol[tt]);
    }
  }
}

// ---------------- xwd: xwdh = fp16(dis * (hfin @ gw)), 16 rows/block ----------------
__global__ __launch_bounds__(256) void xwd_k(const __half* __restrict__ hfin,
                                             const float* __restrict__ gw,
                                             const float* __restrict__ dis,
                                             __half* __restrict__ xwdh) {
  __shared__ float gwS[Fd * Cc];
  for (int i = threadIdx.x; i < Fd * Cc; i += 256) gwS[i] = gw[i];
  __syncthreads();
  int row = blockIdx.x * 16 + (threadIdx.x >> 4);
  int l = threadIdx.x & 15;
  uint4 hv = *(const uint4*)(hfin + (size_t)row * Fd + l * 8);
  const __half2* hp = (const __half2*)&hv;
  float xv[8];
  #pragma unroll
  for (int q = 0; q < 4; ++q) {
    float2 v = __half22float2(hp[q]);
    xv[2 * q] = v.x; xv[2 * q + 1] = v.y;
  }
  float p[Cc];
  #pragma unroll
  for (int c = 0; c < Cc; ++c) p[c] = 0.f;
  #pragma unroll
  for (int i = 0; i < 8; ++i) {
    const float* wr = &gwS[(l * 8 + i) * Cc];
    float x = xv[i];
    #pragma unroll
    for (int c = 0; c < Cc; ++c) p[c] = fmaf(x, wr[c], p[c]);
  }
  #pragma unroll
  for (int m = 8; m >= 1; m >>= 1)
    #pragma unroll
    for (int c = 0; c < Cc; ++c) p[c] += __shfl_xor(p[c], m);
  if (l < 10) {
    float dvr = dis[row];
    *(__half2*)(xwdh + (size_t)row * 32 + 2 * l) =
        __floats2half2_rn(p[2 * l] * dvr, p[2 * l + 1] * dvr);
  }
}

// ---------------- GCN output ----------------
__global__ __launch_bounds__(256) void gcn_out_k(const __half* __restrict__ xwdh,
                                                 const int* __restrict__ row_ptr,
                                                 const uint2* __restrict__ cole,
                                                 const float* __restrict__ dis,
                                                 const float* __restrict__ bias,
                                                 float* __restrict__ out) {
  int node = blockIdx.x * 4 + (threadIdx.x >> 6);
  int lane = threadIdx.x & 63;
  int grp = lane / Cc, c = lane % Cc;       // grp 0..2 active, 3 = idle tail lanes
  float dv = dis[node];
  float acc = 0.f;
  int beg = row_ptr[node], end = row_ptr[node + 1];
  if (grp < 3) {
    for (int j = beg + grp; j < end; j += 3) {
      uint2 ce = cole[j];
      acc += __uint_as_float(ce.y) * __half2float(xwdh[(size_t)ce.x * 32 + c]);
    }
  }
  int l20 = lane + 20 < 64 ? lane + 20 : lane;
  int l40 = lane + 40 < 64 ? lane + 40 : lane;
  float tot = acc + __shfl(acc, l20) + __shfl(acc, l40);
  float val = 0.f;
  if (lane < Cc)
    val = dv * tot + dv * __half2float(xwdh[(size_t)node * 32 + c]) + bias[c];
  float red = (lane < Cc) ? val : -INFINITY;
  #pragma unroll
  for (int m = 32; m >= 1; m >>= 1) red = fmaxf(red, __shfl_xor(red, m));
  float ex = (lane < Cc) ? __expf(val - red) : 0.f;
  #pragma unroll
  for (int m = 32; m >= 1; m >>= 1) ex += __shfl_xor(ex, m);
  float ls = __logf(ex);
  if (lane < Cc) out[(size_t)node * Cc + c] = val - red - ls;
}

// ---------------- host ----------------
extern "C" void kernel_launch(void* const* d_in, const int* in_sizes, int n_in,
                              void* d_out, int out_size, void* d_ws, size_t ws_size,
                              hipStream_t stream) {
  const int*   x_ids = (const int*)d_in[0];
  const int*   ei    = (const int*)d_in[1];
  const int*   srcp  = ei;
  const int*   dstp  = ei + Ee;
  const float* eattr = (const float*)d_in[2];
  const float* emb   = (const float*)d_in[3];
  const float* ln_g  = (const float*)d_in[4];
  const float* ln_b  = (const float*)d_in[5];
  const float* tpar  = (const float*)d_in[6];
  const float* w1    = (const float*)d_in[7];
  const float* b1    = (const float*)d_in[8];
  const float* mg    = (const float*)d_in[9];
  const float* mb    = (const float*)d_in[10];
  const float* w2    = (const float*)d_in[11];
  const float* b2    = (const float*)d_in[12];
  const float* gw    = (const float*)d_in[13];
  const float* gb    = (const float*)d_in[14];
  float* out = (float*)d_out;

  char* ws = (char*)d_ws;
  float* h    = (float*)ws;  ws += (size_t)Nn * Fd * 4;
  __half* xnh = (__half*)ws; ws += (size_t)Nn * Fd * 2;
  __half* xwdh = (__half*)ws; ws += (size_t)Nn * 32 * 2;
  __half* hfin = (__half*)ws; ws += (size_t)Nn * Fd * 2;
  float* dis  = (float*)ws;  ws += (size_t)Nn * 4;
  unsigned short* h2b = (unsigned short*)ws; ws += (size_t)Nn * Fd * 2;
  unsigned short* w1h = (unsigned short*)ws; ws += (size_t)3 * Fd * Hid * 2;
  unsigned short* w2h = (unsigned short*)ws; ws += (size_t)3 * Fd * Hid * 2;
  int* row_ptr = (int*)ws; ws += (size_t)(Nn + 16) * 4;
  int* cnt   = (int*)ws;   ws += (size_t)Nn * 4;        // counts
  int* rank  = (int*)ws;   ws += (size_t)Ee * 4;        // per-edge rank
  uint2* cole = (uint2*)ws; ws += (size_t)Ee * 8;
  int* bsum  = (int*)ws;   ws += 256 * 4;
  if ((size_t)(ws - (char*)d_ws) > ws_size) return;  // workspace too small

  constexpr int NB = (Nn + 255) / 256;  // 157

  prep_w_k<<<(3 * Fd * Hid + 255) / 256, 256, 0, stream>>>(w1, w2, w1h, w2h);

  // CSR by destination (rebuilt every call; deterministic positions via rank)
  zero_int_k<<<NB, 256, 0, stream>>>(cnt, Nn);
  count_k<<<2500, 256, 0, stream>>>(dstp, cnt, rank);
  blocksum_k<<<NB, 256, 0, stream>>>(cnt, bsum, Nn);
  scanbsum_k<<<1, 256, 0, stream>>>(bsum, NB);
  scanfinal_k<<<NB, 256, 0, stream>>>(cnt, bsum, row_ptr, Nn);
  scatter_k<<<2500, 256, 0, stream>>>(srcp, dstp, eattr, row_ptr, rank, cole);
  deg_dis_k<<<NB, 256, 0, stream>>>(row_ptr, cole, dis);

  embed_ln_k<<<Nn / 4, 256, 0, stream>>>(x_ids, emb, ln_g, ln_b, h, xnh);

  for (int i = 0; i < 3; ++i) {
    gen_agg_k<<<Nn / 16, 256, 0, stream>>>(xnh, row_ptr, cole, tpar + i, h2b);
    if (i < 2) {
      mlp0_k<<<Nn / 32, 256, 0, stream>>>(h2b,
          w1h + (size_t)i * Fd * Hid,
          b1 + i * Hid, mg + i * Hid, mb + i * Hid,
          w2h + (size_t)i * Fd * Hid, b2 + i * Fd, h,
          ln_g + (i + 1) * Fd, ln_b + (i + 1) * Fd, xnh);
    } else {
      mlp2_k<<<Nn / 32, 256, 0, stream>>>(h2b,
          w1h + (size_t)i * Fd * Hid,
          b1 + i * Hid, mg + i * Hid, mb + i * Hid,
          w2h + (size_t)i * Fd * Hid, b2 + i * Fd, h, hfin);
    }
  }

  xwd_k<<<Nn / 16, 256, 0, stream>>>(hfin, gw, dis, xwdh);
  gcn_out_k<<<Nn / 4, 256, 0, stream>>>(xwdh, row_ptr, cole, dis, gb, out);
}

// Round 24
// 277.322 us; speedup vs baseline: 1.0591x; 1.0591x over previous
//
#include <hip/hip_runtime.h>
#include <hip/hip_fp16.h>
#include <math.h>

// Problem constants (fixed by the reference)
constexpr int Nn  = 40000;
constexpr int Ee  = 640000;
constexpr int Fd  = 128;
constexpr int Hid = 256;
constexpr int Cc  = 20;
constexpr float GEN_EPS = 1e-7f;
constexpr float LN_EPS  = 1e-5f;

using bfrag = __attribute__((ext_vector_type(8))) short;   // 8 bf16 (4 VGPR)
using f32x4 = __attribute__((ext_vector_type(4))) float;   // 4 fp32 acc
typedef __attribute__((ext_vector_type(4))) unsigned short us4;

__device__ __forceinline__ unsigned short f2bf(float f) {
  unsigned u = __float_as_uint(f);
  u += 0x7FFF + ((u >> 16) & 1);          // RNE
  return (unsigned short)(u >> 16);
}

// ---------------- CSR build ----------------
__global__ void zero_int_k(int* __restrict__ p, int n) {
  int i = blockIdx.x * 256 + threadIdx.x;
  if (i < n) p[i] = 0;
}

// counts + per-edge rank (stable position within its dst segment)
__global__ void count_k(const int* __restrict__ dst, int* __restrict__ cnt,
                        int* __restrict__ rank) {
  int e = blockIdx.x * 256 + threadIdx.x;
  if (e < Ee) rank[e] = atomicAdd(&cnt[dst[e]], 1);
}

__device__ __forceinline__ int block_incl_scan256(int v) {
  int t = threadIdx.x, lane = t & 63, wid = t >> 6;
  int x = v;
  #pragma unroll
  for (int off = 1; off < 64; off <<= 1) {
    int y = __shfl_up(x, off);
    if (lane >= off) x += y;
  }
  __shared__ int wsum[4];
  if (lane == 63) wsum[wid] = x;
  __syncthreads();
  int add = 0;
  #pragma unroll
  for (int w = 0; w < 4; ++w) if (w < wid) add += wsum[w];
  return x + add;
}

__global__ __launch_bounds__(256) void blocksum_k(const int* __restrict__ cnt,
                                                  int* __restrict__ bsum, int n) {
  int i = blockIdx.x * 256 + threadIdx.x;
  int v = (i < n) ? cnt[i] : 0;
  int lane = threadIdx.x & 63, wid = threadIdx.x >> 6;
  #pragma unroll
  for (int m = 32; m >= 1; m >>= 1) v += __shfl_xor(v, m);
  __shared__ int s4[4];
  if (lane == 0) s4[wid] = v;
  __syncthreads();
  if (threadIdx.x == 0) bsum[blockIdx.x] = s4[0] + s4[1] + s4[2] + s4[3];
}

__global__ __launch_bounds__(256) void scanbsum_k(int* __restrict__ bsum, int nb) {
  int t = threadIdx.x;
  int v = (t < nb) ? bsum[t] : 0;
  int incl = block_incl_scan256(v);
  if (t < nb) bsum[t] = incl - v;   // exclusive
}

__global__ __launch_bounds__(256) void scanfinal_k(const int* __restrict__ cnt,
                                                   const int* __restrict__ bsum,
                                                   int* __restrict__ row_ptr, int n) {
  int b = blockIdx.x, t = threadIdx.x;
  int i = b * 256 + t;
  int v = (i < n) ? cnt[i] : 0;
  int incl = block_incl_scan256(v);
  if (i < n) row_ptr[i + 1] = bsum[b] + incl;
  if (b == 0 && t == 0) row_ptr[0] = 0;
}

// atomic-free scatter: position = row_ptr[dst] + precomputed rank
__global__ void scatter_k(const int* __restrict__ src, const int* __restrict__ dst,
                          const float* __restrict__ eattr,
                          const int* __restrict__ row_ptr, const int* __restrict__ rank,
                          uint2* __restrict__ cole) {
  int e = blockIdx.x * 256 + threadIdx.x;
  if (e >= Ee) return;
  int d = dst[e];
  int p = row_ptr[d] + rank[e];
  cole[p] = make_uint2((unsigned)src[e], __float_as_uint(eattr[e]));
}

// deg (incl self loop) -> dis = rsqrt(deg)
__global__ void deg_dis_k(const int* __restrict__ row_ptr, const uint2* __restrict__ cole,
                          float* __restrict__ dis) {
  int i = blockIdx.x * 256 + threadIdx.x;
  if (i >= Nn) return;
  int b = row_ptr[i], e = row_ptr[i + 1];
  float s = 1.f;                         // self-loop weight
  for (int j = b; j < e; ++j) s += __uint_as_float(cole[j].y);
  dis[i] = (s > 0.f) ? rsqrtf(s) : 0.f;
}

// ---------------- weight prep: fp32 -> MFMA-fragment-ordered bf16 (hi plane only) ----------------
__global__ void prep_w_k(const float* __restrict__ w1, const float* __restrict__ w2,
                         unsigned short* __restrict__ w1h, unsigned short* __restrict__ w2h) {
  int i = blockIdx.x * 256 + threadIdx.x;
  constexpr int TOT = 3 * Fd * Hid;   // 98304
  if (i >= TOT) return;
  int j = i & 7, l = (i >> 3) & 63, tk = (i >> 9) & 63, layer = i >> 15;
  int k_lo = (l >> 4) * 4 + (j & 3) + 16 * (j >> 2);
  {
    int kc = tk >> 4, tt = tk & 15;          // w1: K=128 (kc<4), N=256 (tt<16)
    int k = kc * 32 + k_lo, c = tt * 16 + (l & 15);
    w1h[i] = f2bf(w1[((size_t)layer * Fd + k) * Hid + c]);
  }
  {
    int kc = tk >> 3, tt = tk & 7;           // w2: K=256 (kc<8), N=128 (tt<8)
    int k = kc * 32 + k_lo, c = tt * 16 + (l & 15);
    w2h[i] = f2bf(w2[((size_t)layer * Hid + k) * Fd + c]);
  }
}

// ---------------- fused embedding gather + layer-0 LN/ReLU ----------------
__global__ __launch_bounds__(256) void embed_ln_k(const int* __restrict__ ids,
                                                  const float* __restrict__ emb,
                                                  const float* __restrict__ g,
                                                  const float* __restrict__ b,
                                                  float* __restrict__ h,
                                                  __half* __restrict__ xnh) {
  int node = blockIdx.x * 4 + (threadIdx.x >> 6);
  int lane = threadIdx.x & 63;
  float2 v = *(const float2*)(emb + (size_t)ids[node] * Fd + lane * 2);
  *(float2*)(h + (size_t)node * Fd + lane * 2) = v;
  float s = v.x + v.y;
  #pragma unroll
  for (int m = 32; m >= 1; m >>= 1) s += __shfl_xor(s, m);
  float mu = s * (1.f / 128.f);
  float d0 = v.x - mu, d1 = v.y - mu;
  float q = d0 * d0 + d1 * d1;
  #pragma unroll
  for (int m = 32; m >= 1; m >>= 1) q += __shfl_xor(q, m);
  float rs = rsqrtf(q * (1.f / 128.f) + LN_EPS);
  float2 gg = *(const float2*)(g + lane * 2);
  float2 bb = *(const float2*)(b + lane * 2);
  float ox = fmaxf(d0 * rs * gg.x + bb.x, 0.f);
  float oy = fmaxf(d1 * rs * gg.y + bb.y, 0.f);
  *(__half2*)(xnh + (size_t)node * Fd + lane * 2) = __floats2half2_rn(ox, oy);
}

// ---------------- GENConv aggregation: 4 nodes/wave, 8 features/lane -> bf16 h2 ----------------
__global__ __launch_bounds__(256) void gen_agg_k(const __half* __restrict__ xnh,
                                                 const int* __restrict__ row_ptr,
                                                 const uint2* __restrict__ cole,
                                                 const float* __restrict__ t_ptr,
                                                 unsigned short* __restrict__ h2b) {
  int wid = blockIdx.x * 4 + (threadIdx.x >> 6);
  int lane = threadIdx.x & 63;
  int sub = lane >> 4;
  int node = wid * 4 + sub;
  int f0 = (lane & 15) * 8;
  float t = t_ptr[0];
  int beg = row_ptr[node], end = row_ptr[node + 1];
  const __half* xb = xnh + f0;
  float se[8], sm[8];
  #pragma unroll
  for (int i = 0; i < 8; ++i) { se[i] = 0.f; sm[i] = 0.f; }

  for (int j = beg; j < end; j += 8) {
    int idx[8];
    #pragma unroll
    for (int k = 0; k < 8; ++k) idx[k] = (j + k < end) ? (int)cole[j + k].x : -1;
    uint4 hv[8];
    #pragma unroll
    for (int k = 0; k < 8; ++k)
      if (idx[k] >= 0) hv[k] = *(const uint4*)(xb + (size_t)idx[k] * Fd);
    #pragma unroll
    for (int k = 0; k < 8; ++k) {
      if (idx[k] >= 0) {
        const __half2* hp = (const __half2*)&hv[k];
        #pragma unroll
        for (int q = 0; q < 4; ++q) {
          float2 v = __half22float2(hp[q]);
          float m0 = v.x + GEN_EPS, m1 = v.y + GEN_EPS;
          float e0 = __expf(t * m0), e1 = __expf(t * m1);
          se[2 * q]     += e0;  se[2 * q + 1] += e1;
          sm[2 * q]      = fmaf(m0, e0, sm[2 * q]);
          sm[2 * q + 1]  = fmaf(m1, e1, sm[2 * q + 1]);
        }
      }
    }
  }

  // self/residual term from fp16 row; output bf16 (one 16B store)
  uint4 sv = *(const uint4*)(xb + (size_t)node * Fd);
  const __half2* sp2 = (const __half2*)&sv;
  unsigned short ob[8];
  #pragma unroll
  for (int q = 0; q < 4; ++q) {
    float2 sf = __half22float2(sp2[q]);
    ob[2 * q]     = f2bf(sf.x + sm[2 * q]     / (se[2 * q]     + 1e-16f));
    ob[2 * q + 1] = f2bf(sf.y + sm[2 * q + 1] / (se[2 * q + 1] + 1e-16f));
  }
  *(uint4*)(h2b + (size_t)node * Fd + f0) = *(uint4*)ob;
}

// ======== fused MLP core (phase 1: z = relu(LN(h2@W1+b1)) in LDS; phase 2: z@W2) ========
// 32-row tile, 4 waves: rg = row group (16 rows), cg = col group.
// Phase 1 N-split: 2 x 128 cols; phase 2 N-split: 2 x 64 cols.
// z stored in LDS in MFMA-fragment permutation d(c) = (c&3)+8*((c&15)>>2)+4*((c>>4)&1)+32*(c>>5).
__device__ __forceinline__ void mlp_core(const unsigned short* __restrict__ Az,
                                         const unsigned short* __restrict__ W1h,
                                         const float* __restrict__ b1,
                                         const float* __restrict__ g1,
                                         const float* __restrict__ bl1,
                                         const unsigned short* __restrict__ W2h,
                                         int r0,
                                         unsigned short (*Ab)[136],
                                         unsigned short (*Zl)[264],
                                         float (*sred)[32][2],
                                         f32x4* acc2) {
  const int t = threadIdx.x;
  const int w = t >> 6, l = t & 63;
  const int rg = w & 1, cg = w >> 1;
  const int g4 = l >> 4, cl = l & 15;

  // stage h2 (K=128 bf16) fragment-permuted
  {
    int row = t >> 3;
    int base = (t & 7) * 16;
    const unsigned short* sp = Az + (size_t)(r0 + row) * Fd + base;
    #pragma unroll
    for (int hb = 0; hb < 2; ++hb) {
      int kk0 = base + hb * 8;
      uint4 a = *(const uint4*)(sp + hb * 8);
      int chunk = kk0 >> 5, ww = kk0 & 31;
      int d = chunk * 32 + 8 * ((ww & 15) >> 2) + 4 * (ww >> 4);
      us4 v0 = {(unsigned short)a.x, (unsigned short)(a.x >> 16),
                (unsigned short)a.y, (unsigned short)(a.y >> 16)};
      us4 v1 = {(unsigned short)a.z, (unsigned short)(a.z >> 16),
                (unsigned short)a.w, (unsigned short)(a.w >> 16)};
      *(us4*)&Ab[row][d] = v0;
      *(us4*)&Ab[row][d + 8] = v1;
    }
  }
  __syncthreads();

  // phase 1 MFMA: 8 col tiles of this cg's 128 cols
  f32x4 acc[8];
  #pragma unroll
  for (int i = 0; i < 8; ++i) acc[i] = (f32x4){0.f, 0.f, 0.f, 0.f};
  for (int kc = 0; kc < 4; ++kc) {
    bfrag ab = *(const bfrag*)&Ab[16 * rg + cl][kc * 32 + g4 * 8];
    const unsigned short* bh = W1h + ((size_t)(kc * 16 + cg * 8) * 64 + l) * 8;
    #pragma unroll
    for (int tt = 0; tt < 8; ++tt) {
      bfrag vbh = *(const bfrag*)(bh + tt * 512);
      acc[tt] = __builtin_amdgcn_mfma_f32_16x16x32_bf16(ab, vbh, acc[tt], 0, 0, 0);
    }
  }

  // LN pass 1: +bias, per-row partial (s,q) over this wave's 128 cols
  float bcol[8], gcol[8], blc[8];
  #pragma unroll
  for (int tt = 0; tt < 8; ++tt) {
    int c = cg * 128 + 16 * tt + cl;
    bcol[tt] = b1[c]; gcol[tt] = g1[c]; blc[tt] = bl1[c];
  }
  #pragma unroll
  for (int j = 0; j < 4; ++j) {
    float s = 0.f, q = 0.f;
    #pragma unroll
    for (int tt = 0; tt < 8; ++tt) {
      float x = acc[tt][j] + bcol[tt];
      acc[tt][j] = x;
      s += x;
      q = fmaf(x, x, q);
    }
    #pragma unroll
    for (int m = 8; m >= 1; m >>= 1) { s += __shfl_xor(s, m); q += __shfl_xor(q, m); }
    if (cl == 0) {
      int rl = 16 * rg + 4 * g4 + j;
      sred[cg][rl][0] = s;
      sred[cg][rl][1] = q;
    }
  }
  __syncthreads();
  // LN pass 2: combine, normalize, relu, write z to LDS fragment-permuted
  #pragma unroll
  for (int j = 0; j < 4; ++j) {
    int rl = 16 * rg + 4 * g4 + j;
    float s = sred[0][rl][0] + sred[1][rl][0];
    float q = sred[0][rl][1] + sred[1][rl][1];
    float mu = s * (1.f / 256.f);
    float rs = rsqrtf(q * (1.f / 256.f) - mu * mu + LN_EPS);
    #pragma unroll
    for (int tt = 0; tt < 8; ++tt) {
      float z = fmaxf((acc[tt][j] - mu) * rs * gcol[tt] + blc[tt], 0.f);
      int d = (cl & 3) + 8 * (cl >> 2) + 4 * (tt & 1) + 32 * ((tt >> 1) + 4 * cg);
      Zl[rl][d] = f2bf(z);
    }
  }
  __syncthreads();                      // z tile complete (also fences sred reuse)

  // phase 2 MFMA: 4 col tiles of this cg's 64 cols, K=256 from Zl
  #pragma unroll
  for (int i = 0; i < 4; ++i) acc2[i] = (f32x4){0.f, 0.f, 0.f, 0.f};
  for (int kf = 0; kf < 8; ++kf) {
    bfrag ab = *(const bfrag*)&Zl[16 * rg + cl][kf * 32 + g4 * 8];
    const unsigned short* bh = W2h + ((size_t)(kf * 8 + cg * 4) * 64 + l) * 8;
    #pragma unroll
    for (int tt = 0; tt < 4; ++tt) {
      bfrag vbh = *(const bfrag*)(bh + tt * 512);
      acc2[tt] = __builtin_amdgcn_mfma_f32_16x16x32_bf16(ab, vbh, acc2[tt], 0, 0, 0);
    }
  }
}

// ---------------- fused MLP, layers 0/1: H += out + b2; XNh = relu(LN(H)) ----------------
__global__ __launch_bounds__(256) void mlp0_k(const unsigned short* __restrict__ Az,
                                              const unsigned short* __restrict__ W1h,
                                              const float* __restrict__ b1,
                                              const float* __restrict__ g1,
                                              const float* __restrict__ bl1,
                                              const unsigned short* __restrict__ W2h,
                                              const float* __restrict__ b2,
                                              float* __restrict__ H,
                                              const float* __restrict__ gN,
                                              const float* __restrict__ blN,
                                              __half* __restrict__ XNh) {
  __shared__ unsigned short Ab[32][136];
  __shared__ unsigned short Zl[32][264];
  __shared__ float sred[2][32][2];
  const int t = threadIdx.x;
  const int w = t >> 6, l = t & 63;
  const int rg = w & 1, cg = w >> 1;
  const int g4 = l >> 4, cl = l & 15;
  const int r0 = blockIdx.x * 32;

  f32x4 acc2[4];
  mlp_core(Az, W1h, b1, g1, bl1, W2h, r0, Ab, Zl, sred, acc2);

  float bcol[4], gcol[4], blc[4];
  #pragma unroll
  for (int tt = 0; tt < 4; ++tt) {
    int c = cg * 64 + 16 * tt + cl;
    bcol[tt] = b2[c];
    gcol[tt] = gN[c]; blc[tt] = blN[c];
  }
  // pass 1: residual + H write + per-row partials over 64 cols
  #pragma unroll
  for (int j = 0; j < 4; ++j) {
    int row = r0 + 16 * rg + 4 * g4 + j;
    float s = 0.f, q = 0.f;
    #pragma unroll
    for (int tt = 0; tt < 4; ++tt) {
      size_t off = (size_t)row * Fd + cg * 64 + 16 * tt + cl;
      float hv = H[off] + acc2[tt][j] + bcol[tt];
      H[off] = hv;
      acc2[tt][j] = hv;
      s += hv;
      q = fmaf(hv, hv, q);
    }
    #pragma unroll
    for (int m = 8; m >= 1; m >>= 1) { s += __shfl_xor(s, m); q += __shfl_xor(q, m); }
    if (cl == 0) {
      int rl = 16 * rg + 4 * g4 + j;
      sred[cg][rl][0] = s;
      sred[cg][rl][1] = q;
    }
  }
  __syncthreads();
  // pass 2: combine, normalize, write fp16
  #pragma unroll
  for (int j = 0; j < 4; ++j) {
    int rl = 16 * rg + 4 * g4 + j;
    float s = sred[0][rl][0] + sred[1][rl][0];
    float q = sred[0][rl][1] + sred[1][rl][1];
    float mu = s * (1.f / 128.f);
    float rs = rsqrtf(q * (1.f / 128.f) - mu * mu + LN_EPS);
    int row = r0 + rl;
    #pragma unroll
    for (int tt = 0; tt < 4; ++tt) {
      float z = fmaxf((acc2[tt][j] - mu) * rs * gcol[tt] + blc[tt], 0.f);
      XNh[(size_t)row * Fd + cg * 64 + 16 * tt + cl] = __float2half_rn(z);
    }
  }
}

// ---------------- fused MLP, last layer: xwdh = fp16(dis * ((H + out + b2) @ gw)) ----------------
__global__ __launch_bounds__(256) void mlp2_k(const unsigned short* __restrict__ Az,
                                              const unsigned short* __restrict__ W1h,
                                              const float* __restrict__ b1,
                                              const float* __restrict__ g1,
                                              const float* __restrict__ bl1,
                                              const unsigned short* __restrict__ W2h,
                                              const float* __restrict__ b2,
                                              const float* __restrict__ H,
                                              const float* __restrict__ gw,
                                              const float* __restrict__ dis,
                                              __half* __restrict__ xwdh) {
  __shared__ unsigned short Ab[32][136];
  __shared__ unsigned short Zl[32][264];
  __shared__ float sred[2][32][2];
  __shared__ float pred[2][32][20];
  __shared__ float gwS[Fd * Cc];
  const int t = threadIdx.x;
  const int w = t >> 6, l = t & 63;
  const int rg = w & 1, cg = w >> 1;
  const int g4 = l >> 4, cl = l & 15;
  const int r0 = blockIdx.x * 32;

  for (int i = t; i < Fd * Cc; i += 256) gwS[i] = gw[i];   // before first barrier in core

  f32x4 acc2[4];
  mlp_core(Az, W1h, b1, g1, bl1, W2h, r0, Ab, Zl, sred, acc2);

  float bcol[4];
  #pragma unroll
  for (int tt = 0; tt < 4; ++tt) bcol[tt] = b2[cg * 64 + 16 * tt + cl];

  // pass 1: per-(row,colgroup) partial p[20]
  #pragma unroll
  for (int j = 0; j < 4; ++j) {
    int row = r0 + 16 * rg + 4 * g4 + j;
    float p[Cc];
    #pragma unroll
    for (int c = 0; c < Cc; ++c) p[c] = 0.f;
    #pragma unroll
    for (int tt = 0; tt < 4; ++tt) {
      size_t off = (size_t)row * Fd + cg * 64 + 16 * tt + cl;
      float xv = H[off] + acc2[tt][j] + bcol[tt];
      const float* wr = &gwS[(cg * 64 + 16 * tt + cl) * Cc];
      #pragma unroll
      for (int c = 0; c < Cc; ++c) p[c] = fmaf(xv, wr[c], p[c]);
    }
    #pragma unroll
    for (int c = 0; c < Cc; ++c) {
      #pragma unroll
      for (int m = 8; m >= 1; m >>= 1) p[c] += __shfl_xor(p[c], m);
    }
    int rl = 16 * rg + 4 * g4 + j;
    if (cl < 10) {
      pred[cg][rl][2 * cl]     = p[2 * cl];
      pred[cg][rl][2 * cl + 1] = p[2 * cl + 1];
    }
  }
  __syncthreads();
  // pass 2: colgroup 0 combines and writes fp16x2
  if (cg == 0) {
    #pragma unroll
    for (int j = 0; j < 4; ++j) {
      int rl = 16 * rg + 4 * g4 + j;
      int row = r0 + rl;
      float dvr = dis[row];
      if (cl < 10) {
        float v0 = (pred[0][rl][2 * cl]     + pred[1][rl][2 * cl])     * dvr;
        float v1 = (pred[0][rl][2 * cl + 1] + pred[1][rl][2 * cl + 1]) * dvr;
        *(__half2*)(xwdh + (size_t)row * 32 + 2 * cl) = __floats2half2_rn(v0, v1);
      }
    }
  }
}

// ---------------- GCN output ----------------
__global__ __launch_bounds__(256) void gcn_out_k(const __half* __restrict__ xwdh,
                                                 const int* __restrict__ row_ptr,
                                                 const uint2* __restrict__ cole,
                                                 const float* __restrict__ dis,
                                                 const float* __restrict__ bias,
                                                 float* __restrict__ out) {
  int node = blockIdx.x * 4 + (threadIdx.x >> 6);
  int lane = threadIdx.x & 63;
  int grp = lane / Cc, c = lane % Cc;       // grp 0..2 active, 3 = idle tail lanes
  float dv = dis[node];
  float acc = 0.f;
  int beg = row_ptr[node], end = row_ptr[node + 1];
  if (grp < 3) {
    for (int j = beg + grp; j < end; j += 3) {
      uint2 ce = cole[j];
      acc += __uint_as_float(ce.y) * __half2float(xwdh[(size_t)ce.x * 32 + c]);
    }
  }
  int l20 = lane + 20 < 64 ? lane + 20 : lane;
  int l40 = lane + 40 < 64 ? lane + 40 : lane;
  float tot = acc + __shfl(acc, l20) + __shfl(acc, l40);
  float val = 0.f;
  if (lane < Cc)
    val = dv * tot + dv * __half2float(xwdh[(size_t)node * 32 + c]) + bias[c];
  float red = (lane < Cc) ? val : -INFINITY;
  #pragma unroll
  for (int m = 32; m >= 1; m >>= 1) red = fmaxf(red, __shfl_xor(red, m));
  float ex = (lane < Cc) ? __expf(val - red) : 0.f;
  #pragma unroll
  for (int m = 32; m >= 1; m >>= 1) ex += __shfl_xor(ex, m);
  float ls = __logf(ex);
  if (lane < Cc) out[(size_t)node * Cc + c] = val - red - ls;
}

// ---------------- host ----------------
extern "C" void kernel_launch(void* const* d_in, const int* in_sizes, int n_in,
                              void* d_out, int out_size, void* d_ws, size_t ws_size,
                              hipStream_t stream) {
  const int*   x_ids = (const int*)d_in[0];
  const int*   ei    = (const int*)d_in[1];
  const int*   srcp  = ei;
  const int*   dstp  = ei + Ee;
  const float* eattr = (const float*)d_in[2];
  const float* emb   = (const float*)d_in[3];
  const float* ln_g  = (const float*)d_in[4];
  const float* ln_b  = (const float*)d_in[5];
  const float* tpar  = (const float*)d_in[6];
  const float* w1    = (const float*)d_in[7];
  const float* b1    = (const float*)d_in[8];
  const float* mg    = (const float*)d_in[9];
  const float* mb    = (const float*)d_in[10];
  const float* w2    = (const float*)d_in[11];
  const float* b2    = (const float*)d_in[12];
  const float* gw    = (const float*)d_in[13];
  const float* gb    = (const float*)d_in[14];
  float* out = (float*)d_out;

  char* ws = (char*)d_ws;
  float* h    = (float*)ws;  ws += (size_t)Nn * Fd * 4;
  __half* xnh = (__half*)ws; ws += (size_t)Nn * Fd * 2;
  __half* xwdh = (__half*)ws; ws += (size_t)Nn * 32 * 2;
  float* dis  = (float*)ws;  ws += (size_t)Nn * 4;
  unsigned short* h2b = (unsigned short*)ws; ws += (size_t)Nn * Fd * 2;
  unsigned short* w1h = (unsigned short*)ws; ws += (size_t)3 * Fd * Hid * 2;
  unsigned short* w2h = (unsigned short*)ws; ws += (size_t)3 * Fd * Hid * 2;
  int* row_ptr = (int*)ws; ws += (size_t)(Nn + 16) * 4;
  int* cnt   = (int*)ws;   ws += (size_t)Nn * 4;        // counts
  int* rank  = (int*)ws;   ws += (size_t)Ee * 4;        // per-edge rank
  uint2* cole = (uint2*)ws; ws += (size_t)Ee * 8;
  int* bsum  = (int*)ws;   ws += 256 * 4;
  if ((size_t)(ws - (char*)d_ws) > ws_size) return;  // workspace too small

  constexpr int NB = (Nn + 255) / 256;  // 157

  prep_w_k<<<(3 * Fd * Hid + 255) / 256, 256, 0, stream>>>(w1, w2, w1h, w2h);

  // CSR by destination (rebuilt every call; deterministic positions via rank)
  zero_int_k<<<NB, 256, 0, stream>>>(cnt, Nn);
  count_k<<<2500, 256, 0, stream>>>(dstp, cnt, rank);
  blocksum_k<<<NB, 256, 0, stream>>>(cnt, bsum, Nn);
  scanbsum_k<<<1, 256, 0, stream>>>(bsum, NB);
  scanfinal_k<<<NB, 256, 0, stream>>>(cnt, bsum, row_ptr, Nn);
  scatter_k<<<2500, 256, 0, stream>>>(srcp, dstp, eattr, row_ptr, rank, cole);
  deg_dis_k<<<NB, 256, 0, stream>>>(row_ptr, cole, dis);

  embed_ln_k<<<Nn / 4, 256, 0, stream>>>(x_ids, emb, ln_g, ln_b, h, xnh);

  for (int i = 0; i < 3; ++i) {
    gen_agg_k<<<Nn / 16, 256, 0, stream>>>(xnh, row_ptr, cole, tpar + i, h2b);
    if (i < 2) {
      mlp0_k<<<Nn / 32, 256, 0, stream>>>(h2b,
          w1h + (size_t)i * Fd * Hid,
          b1 + i * Hid, mg + i * Hid, mb + i * Hid,
          w2h + (size_t)i * Fd * Hid, b2 + i * Fd, h,
          ln_g + (i + 1) * Fd, ln_b + (i + 1) * Fd, xnh);
    } else {
      mlp2_k<<<Nn / 32, 256, 0, stream>>>(h2b,
          w1h + (size_t)i * Fd * Hid,
          b1 + i * Hid, mg + i * Hid, mb + i * Hid,
          w2h + (size_t)i * Fd * Hid, b2 + i * Fd, h,
          gw, dis, xwdh);
    }
  }

  gcn_out_k<<<Nn / 4, 256, 0, stream>>>(xwdh, row_ptr, cole, dis, gb, out);
}

// Round 25
// 256.360 us; speedup vs baseline: 1.1457x; 1.0818x over previous
//
#include <hip/hip_runtime.h>
#include <hip/hip_fp16.h>
#include <math.h>

// Problem constants (fixed by the reference)
constexpr int Nn  = 40000;
constexpr int Ee  = 640000;
constexpr int Fd  = 128;
constexpr int Hid = 256;
constexpr int Cc  = 20;
constexpr float GEN_EPS = 1e-7f;
constexpr float LN_EPS  = 1e-5f;

using bfrag = __attribute__((ext_vector_type(8))) short;   // 8 bf16 (4 VGPR)
using f32x4 = __attribute__((ext_vector_type(4))) float;   // 4 fp32 acc
typedef __attribute__((ext_vector_type(4))) unsigned short us4;

__device__ __forceinline__ unsigned short f2bf(float f) {
  unsigned u = __float_as_uint(f);
  u += 0x7FFF + ((u >> 16) & 1);          // RNE
  return (unsigned short)(u >> 16);
}

// ---------------- CSR build ----------------
__global__ void zero_int_k(int* __restrict__ p, int n) {
  int i = blockIdx.x * 256 + threadIdx.x;
  if (i < n) p[i] = 0;
}

// counts + per-edge rank (stable position within its dst segment)
__global__ void count_k(const int* __restrict__ dst, int* __restrict__ cnt,
                        int* __restrict__ rank) {
  int e = blockIdx.x * 256 + threadIdx.x;
  if (e < Ee) rank[e] = atomicAdd(&cnt[dst[e]], 1);
}

__device__ __forceinline__ int block_incl_scan256(int v) {
  int t = threadIdx.x, lane = t & 63, wid = t >> 6;
  int x = v;
  #pragma unroll
  for (int off = 1; off < 64; off <<= 1) {
    int y = __shfl_up(x, off);
    if (lane >= off) x += y;
  }
  __shared__ int wsum[4];
  if (lane == 63) wsum[wid] = x;
  __syncthreads();
  int add = 0;
  #pragma unroll
  for (int w = 0; w < 4; ++w) if (w < wid) add += wsum[w];
  return x + add;
}

__global__ __launch_bounds__(256) void blocksum_k(const int* __restrict__ cnt,
                                                  int* __restrict__ bsum, int n) {
  int i = blockIdx.x * 256 + threadIdx.x;
  int v = (i < n) ? cnt[i] : 0;
  int lane = threadIdx.x & 63, wid = threadIdx.x >> 6;
  #pragma unroll
  for (int m = 32; m >= 1; m >>= 1) v += __shfl_xor(v, m);
  __shared__ int s4[4];
  if (lane == 0) s4[wid] = v;
  __syncthreads();
  if (threadIdx.x == 0) bsum[blockIdx.x] = s4[0] + s4[1] + s4[2] + s4[3];
}

__global__ __launch_bounds__(256) void scanbsum_k(int* __restrict__ bsum, int nb) {
  int t = threadIdx.x;
  int v = (t < nb) ? bsum[t] : 0;
  int incl = block_incl_scan256(v);
  if (t < nb) bsum[t] = incl - v;   // exclusive
}

__global__ __launch_bounds__(256) void scanfinal_k(const int* __restrict__ cnt,
                                                   const int* __restrict__ bsum,
                                                   int* __restrict__ row_ptr, int n) {
  int b = blockIdx.x, t = threadIdx.x;
  int i = b * 256 + t;
  int v = (i < n) ? cnt[i] : 0;
  int incl = block_incl_scan256(v);
  if (i < n) row_ptr[i + 1] = bsum[b] + incl;
  if (b == 0 && t == 0) row_ptr[0] = 0;
}

// atomic-free scatter: position = row_ptr[dst] + precomputed rank
__global__ void scatter_k(const int* __restrict__ src, const int* __restrict__ dst,
                          const float* __restrict__ eattr,
                          const int* __restrict__ row_ptr, const int* __restrict__ rank,
                          uint2* __restrict__ cole) {
  int e = blockIdx.x * 256 + threadIdx.x;
  if (e >= Ee) return;
  int d = dst[e];
  int p = row_ptr[d] + rank[e];
  cole[p] = make_uint2((unsigned)src[e], __float_as_uint(eattr[e]));
}

// deg (incl self loop) -> dis = rsqrt(deg)
__global__ void deg_dis_k(const int* __restrict__ row_ptr, const uint2* __restrict__ cole,
                          float* __restrict__ dis) {
  int i = blockIdx.x * 256 + threadIdx.x;
  if (i >= Nn) return;
  int b = row_ptr[i], e = row_ptr[i + 1];
  float s = 1.f;                         // self-loop weight
  for (int j = b; j < e; ++j) s += __uint_as_float(cole[j].y);
  dis[i] = (s > 0.f) ? rsqrtf(s) : 0.f;
}

// ---------------- weight prep: fp32 -> MFMA-fragment-ordered bf16 ----------------
// also emits gwf: gw[128][20] -> bf16 fragments padded to N=32 (cols 20..31 zero)
__global__ void prep_w_k(const float* __restrict__ w1, const float* __restrict__ w2,
                         const float* __restrict__ gw,
                         unsigned short* __restrict__ w1h, unsigned short* __restrict__ w2h,
                         unsigned short* __restrict__ gwf) {
  int i = blockIdx.x * 256 + threadIdx.x;
  constexpr int TOT = 3 * Fd * Hid;   // 98304
  if (i >= TOT) return;
  int j = i & 7, l = (i >> 3) & 63, tk = (i >> 9) & 63, layer = i >> 15;
  int k_lo = (l >> 4) * 4 + (j & 3) + 16 * (j >> 2);
  {
    int kc = tk >> 4, tt = tk & 15;          // w1: K=128 (kc<4), N=256 (tt<16)
    int k = kc * 32 + k_lo, c = tt * 16 + (l & 15);
    w1h[i] = f2bf(w1[((size_t)layer * Fd + k) * Hid + c]);
  }
  {
    int kc = tk >> 3, tt = tk & 7;           // w2: K=256 (kc<8), N=128 (tt<8)
    int k = kc * 32 + k_lo, c = tt * 16 + (l & 15);
    w2h[i] = f2bf(w2[((size_t)layer * Hid + k) * Fd + c]);
  }
  if (i < 4096) {                            // gwf: K=128 (kc<4), N=32 (tt<2)
    int tk2 = i >> 9;                        // 0..7
    int kc = tk2 >> 1, tt = tk2 & 1;
    int k = kc * 32 + k_lo, c = tt * 16 + (l & 15);
    gwf[i] = (c < Cc) ? f2bf(gw[(size_t)k * Cc + c]) : (unsigned short)0;
  }
}

// ---------------- fused embedding gather + layer-0 LN/ReLU ----------------
__global__ __launch_bounds__(256) void embed_ln_k(const int* __restrict__ ids,
                                                  const float* __restrict__ emb,
                                                  const float* __restrict__ g,
                                                  const float* __restrict__ b,
                                                  float* __restrict__ h,
                                                  __half* __restrict__ xnh) {
  int node = blockIdx.x * 4 + (threadIdx.x >> 6);
  int lane = threadIdx.x & 63;
  float2 v = *(const float2*)(emb + (size_t)ids[node] * Fd + lane * 2);
  *(float2*)(h + (size_t)node * Fd + lane * 2) = v;
  float s = v.x + v.y;
  #pragma unroll
  for (int m = 32; m >= 1; m >>= 1) s += __shfl_xor(s, m);
  float mu = s * (1.f / 128.f);
  float d0 = v.x - mu, d1 = v.y - mu;
  float q = d0 * d0 + d1 * d1;
  #pragma unroll
  for (int m = 32; m >= 1; m >>= 1) q += __shfl_xor(q, m);
  float rs = rsqrtf(q * (1.f / 128.f) + LN_EPS);
  float2 gg = *(const float2*)(g + lane * 2);
  float2 bb = *(const float2*)(b + lane * 2);
  float ox = fmaxf(d0 * rs * gg.x + bb.x, 0.f);
  float oy = fmaxf(d1 * rs * gg.y + bb.y, 0.f);
  *(__half2*)(xnh + (size_t)node * Fd + lane * 2) = __floats2half2_rn(ox, oy);
}

// ---------------- GENConv aggregation: 4 nodes/wave, 8 features/lane -> bf16 h2 ----------------
__global__ __launch_bounds__(256) void gen_agg_k(const __half* __restrict__ xnh,
                                                 const int* __restrict__ row_ptr,
                                                 const uint2* __restrict__ cole,
                                                 const float* __restrict__ t_ptr,
                                                 unsigned short* __restrict__ h2b) {
  int wid = blockIdx.x * 4 + (threadIdx.x >> 6);
  int lane = threadIdx.x & 63;
  int sub = lane >> 4;
  int node = wid * 4 + sub;
  int f0 = (lane & 15) * 8;
  float t = t_ptr[0];
  int beg = row_ptr[node], end = row_ptr[node + 1];
  const __half* xb = xnh + f0;
  float se[8], sm[8];
  #pragma unroll
  for (int i = 0; i < 8; ++i) { se[i] = 0.f; sm[i] = 0.f; }

  for (int j = beg; j < end; j += 8) {
    int idx[8];
    #pragma unroll
    for (int k = 0; k < 8; ++k) idx[k] = (j + k < end) ? (int)cole[j + k].x : -1;
    uint4 hv[8];
    #pragma unroll
    for (int k = 0; k < 8; ++k)
      if (idx[k] >= 0) hv[k] = *(const uint4*)(xb + (size_t)idx[k] * Fd);
    #pragma unroll
    for (int k = 0; k < 8; ++k) {
      if (idx[k] >= 0) {
        const __half2* hp = (const __half2*)&hv[k];
        #pragma unroll
        for (int q = 0; q < 4; ++q) {
          float2 v = __half22float2(hp[q]);
          float m0 = v.x + GEN_EPS, m1 = v.y + GEN_EPS;
          float e0 = __expf(t * m0), e1 = __expf(t * m1);
          se[2 * q]     += e0;  se[2 * q + 1] += e1;
          sm[2 * q]      = fmaf(m0, e0, sm[2 * q]);
          sm[2 * q + 1]  = fmaf(m1, e1, sm[2 * q + 1]);
        }
      }
    }
  }

  // self/residual term from fp16 row; output bf16 (one 16B store)
  uint4 sv = *(const uint4*)(xb + (size_t)node * Fd);
  const __half2* sp2 = (const __half2*)&sv;
  unsigned short ob[8];
  #pragma unroll
  for (int q = 0; q < 4; ++q) {
    float2 sf = __half22float2(sp2[q]);
    ob[2 * q]     = f2bf(sf.x + sm[2 * q]     / (se[2 * q]     + 1e-16f));
    ob[2 * q + 1] = f2bf(sf.y + sm[2 * q + 1] / (se[2 * q + 1] + 1e-16f));
  }
  *(uint4*)(h2b + (size_t)node * Fd + f0) = *(uint4*)ob;
}

// ======== fused MLP core (phase 1: z = relu(LN(h2@W1+b1)) in LDS; phase 2: z@W2) ========
// 32-row tile, 4 waves: rg = row group (16 rows), cg = col group.
// Phase 1 N-split: 2 x 128 cols; phase 2 N-split: 2 x 64 cols.
__device__ __forceinline__ void mlp_core(const unsigned short* __restrict__ Az,
                                         const unsigned short* __restrict__ W1h,
                                         const float* __restrict__ b1,
                                         const float* __restrict__ g1,
                                         const float* __restrict__ bl1,
                                         const unsigned short* __restrict__ W2h,
                                         int r0,
                                         unsigned short (*Ab)[136],
                                         unsigned short (*Zl)[264],
                                         float (*sred)[32][2],
                                         f32x4* acc2) {
  const int t = threadIdx.x;
  const int w = t >> 6, l = t & 63;
  const int rg = w & 1, cg = w >> 1;
  const int g4 = l >> 4, cl = l & 15;

  // stage h2 (K=128 bf16) fragment-permuted
  {
    int row = t >> 3;
    int base = (t & 7) * 16;
    const unsigned short* sp = Az + (size_t)(r0 + row) * Fd + base;
    #pragma unroll
    for (int hb = 0; hb < 2; ++hb) {
      int kk0 = base + hb * 8;
      uint4 a = *(const uint4*)(sp + hb * 8);
      int chunk = kk0 >> 5, ww = kk0 & 31;
      int d = chunk * 32 + 8 * ((ww & 15) >> 2) + 4 * (ww >> 4);
      us4 v0 = {(unsigned short)a.x, (unsigned short)(a.x >> 16),
                (unsigned short)a.y, (unsigned short)(a.y >> 16)};
      us4 v1 = {(unsigned short)a.z, (unsigned short)(a.z >> 16),
                (unsigned short)a.w, (unsigned short)(a.w >> 16)};
      *(us4*)&Ab[row][d] = v0;
      *(us4*)&Ab[row][d + 8] = v1;
    }
  }
  __syncthreads();

  // phase 1 MFMA: 8 col tiles of this cg's 128 cols
  f32x4 acc[8];
  #pragma unroll
  for (int i = 0; i < 8; ++i) acc[i] = (f32x4){0.f, 0.f, 0.f, 0.f};
  for (int kc = 0; kc < 4; ++kc) {
    bfrag ab = *(const bfrag*)&Ab[16 * rg + cl][kc * 32 + g4 * 8];
    const unsigned short* bh = W1h + ((size_t)(kc * 16 + cg * 8) * 64 + l) * 8;
    #pragma unroll
    for (int tt = 0; tt < 8; ++tt) {
      bfrag vbh = *(const bfrag*)(bh + tt * 512);
      acc[tt] = __builtin_amdgcn_mfma_f32_16x16x32_bf16(ab, vbh, acc[tt], 0, 0, 0);
    }
  }

  // LN pass 1: +bias, per-row partial (s,q) over this wave's 128 cols
  float bcol[8], gcol[8], blc[8];
  #pragma unroll
  for (int tt = 0; tt < 8; ++tt) {
    int c = cg * 128 + 16 * tt + cl;
    bcol[tt] = b1[c]; gcol[tt] = g1[c]; blc[tt] = bl1[c];
  }
  #pragma unroll
  for (int j = 0; j < 4; ++j) {
    float s = 0.f, q = 0.f;
    #pragma unroll
    for (int tt = 0; tt < 8; ++tt) {
      float x = acc[tt][j] + bcol[tt];
      acc[tt][j] = x;
      s += x;
      q = fmaf(x, x, q);
    }
    #pragma unroll
    for (int m = 8; m >= 1; m >>= 1) { s += __shfl_xor(s, m); q += __shfl_xor(q, m); }
    if (cl == 0) {
      int rl = 16 * rg + 4 * g4 + j;
      sred[cg][rl][0] = s;
      sred[cg][rl][1] = q;
    }
  }
  __syncthreads();
  // LN pass 2: combine, normalize, relu, write z to LDS fragment-permuted
  #pragma unroll
  for (int j = 0; j < 4; ++j) {
    int rl = 16 * rg + 4 * g4 + j;
    float s = sred[0][rl][0] + sred[1][rl][0];
    float q = sred[0][rl][1] + sred[1][rl][1];
    float mu = s * (1.f / 256.f);
    float rs = rsqrtf(q * (1.f / 256.f) - mu * mu + LN_EPS);
    #pragma unroll
    for (int tt = 0; tt < 8; ++tt) {
      float z = fmaxf((acc[tt][j] - mu) * rs * gcol[tt] + blc[tt], 0.f);
      int d = (cl & 3) + 8 * (cl >> 2) + 4 * (tt & 1) + 32 * ((tt >> 1) + 4 * cg);
      Zl[rl][d] = f2bf(z);
    }
  }
  __syncthreads();                      // z tile complete (also fences sred reuse)

  // phase 2 MFMA: 4 col tiles of this cg's 64 cols, K=256 from Zl
  #pragma unroll
  for (int i = 0; i < 4; ++i) acc2[i] = (f32x4){0.f, 0.f, 0.f, 0.f};
  for (int kf = 0; kf < 8; ++kf) {
    bfrag ab = *(const bfrag*)&Zl[16 * rg + cl][kf * 32 + g4 * 8];
    const unsigned short* bh = W2h + ((size_t)(kf * 8 + cg * 4) * 64 + l) * 8;
    #pragma unroll
    for (int tt = 0; tt < 4; ++tt) {
      bfrag vbh = *(const bfrag*)(bh + tt * 512);
      acc2[tt] = __builtin_amdgcn_mfma_f32_16x16x32_bf16(ab, vbh, acc2[tt], 0, 0, 0);
    }
  }
}

// ---------------- fused MLP, layers 0/1: H += out + b2; XNh = relu(LN(H)) ----------------
__global__ __launch_bounds__(256) void mlp0_k(const unsigned short* __restrict__ Az,
                                              const unsigned short* __restrict__ W1h,
                                              const float* __restrict__ b1,
                                              const float* __restrict__ g1,
                                              const float* __restrict__ bl1,
                                              const unsigned short* __restrict__ W2h,
                                              const float* __restrict__ b2,
                                              float* __restrict__ H,
                                              const float* __restrict__ gN,
                                              const float* __restrict__ blN,
                                              __half* __restrict__ XNh) {
  __shared__ unsigned short Ab[32][136];
  __shared__ unsigned short Zl[32][264];
  __shared__ float sred[2][32][2];
  const int t = threadIdx.x;
  const int w = t >> 6, l = t & 63;
  const int rg = w & 1, cg = w >> 1;
  const int g4 = l >> 4, cl = l & 15;
  const int r0 = blockIdx.x * 32;

  f32x4 acc2[4];
  mlp_core(Az, W1h, b1, g1, bl1, W2h, r0, Ab, Zl, sred, acc2);

  float bcol[4], gcol[4], blc[4];
  #pragma unroll
  for (int tt = 0; tt < 4; ++tt) {
    int c = cg * 64 + 16 * tt + cl;
    bcol[tt] = b2[c];
    gcol[tt] = gN[c]; blc[tt] = blN[c];
  }
  // pass 1: residual + H write + per-row partials over 64 cols
  #pragma unroll
  for (int j = 0; j < 4; ++j) {
    int row = r0 + 16 * rg + 4 * g4 + j;
    float s = 0.f, q = 0.f;
    #pragma unroll
    for (int tt = 0; tt < 4; ++tt) {
      size_t off = (size_t)row * Fd + cg * 64 + 16 * tt + cl;
      float hv = H[off] + acc2[tt][j] + bcol[tt];
      H[off] = hv;
      acc2[tt][j] = hv;
      s += hv;
      q = fmaf(hv, hv, q);
    }
    #pragma unroll
    for (int m = 8; m >= 1; m >>= 1) { s += __shfl_xor(s, m); q += __shfl_xor(q, m); }
    if (cl == 0) {
      int rl = 16 * rg + 4 * g4 + j;
      sred[cg][rl][0] = s;
      sred[cg][rl][1] = q;
    }
  }
  __syncthreads();
  // pass 2: combine, normalize, write fp16
  #pragma unroll
  for (int j = 0; j < 4; ++j) {
    int rl = 16 * rg + 4 * g4 + j;
    float s = sred[0][rl][0] + sred[1][rl][0];
    float q = sred[0][rl][1] + sred[1][rl][1];
    float mu = s * (1.f / 128.f);
    float rs = rsqrtf(q * (1.f / 128.f) - mu * mu + LN_EPS);
    int row = r0 + rl;
    #pragma unroll
    for (int tt = 0; tt < 4; ++tt) {
      float z = fmaxf((acc2[tt][j] - mu) * rs * gcol[tt] + blc[tt], 0.f);
      XNh[(size_t)row * Fd + cg * 64 + 16 * tt + cl] = __float2half_rn(z);
    }
  }
}

// ---------------- fused MLP, last layer: xwdh = fp16(dis*((H+out+b2)@gw)) via 3rd MFMA phase ----------------
__global__ __launch_bounds__(256) void mlp2_k(const unsigned short* __restrict__ Az,
                                              const unsigned short* __restrict__ W1h,
                                              const float* __restrict__ b1,
                                              const float* __restrict__ g1,
                                              const float* __restrict__ bl1,
                                              const unsigned short* __restrict__ W2h,
                                              const float* __restrict__ b2,
                                              const float* __restrict__ H,
                                              const unsigned short* __restrict__ gwf,
                                              const float* __restrict__ dis,
                                              __half* __restrict__ xwdh) {
  __shared__ unsigned short Ab[32][136];
  __shared__ unsigned short Zl[32][264];
  __shared__ float sred[2][32][2];
  const int t = threadIdx.x;
  const int w = t >> 6, l = t & 63;
  const int rg = w & 1, cg = w >> 1;
  const int g4 = l >> 4, cl = l & 15;
  const int r0 = blockIdx.x * 32;

  f32x4 acc2[4];
  mlp_core(Az, W1h, b1, g1, bl1, W2h, r0, Ab, Zl, sred, acc2);

  float bcol[4];
  #pragma unroll
  for (int tt = 0; tt < 4; ++tt) bcol[tt] = b2[cg * 64 + 16 * tt + cl];

  // stage xfin = H + out + b2 into Ab as bf16, K=128 fragment-permuted
  // (Ab last read in phase 1; two barriers since -> safe to overwrite)
  #pragma unroll
  for (int j = 0; j < 4; ++j) {
    int rl = 16 * rg + 4 * g4 + j;
    #pragma unroll
    for (int tt = 0; tt < 4; ++tt) {
      int c = cg * 64 + 16 * tt + cl;
      size_t off = (size_t)(r0 + rl) * Fd + c;
      float xv = H[off] + acc2[tt][j] + bcol[tt];
      int d = 32 * (c >> 5) + 8 * ((c >> 2) & 3) + 4 * ((c >> 4) & 1) + (c & 3);
      Ab[rl][d] = f2bf(xv);
    }
  }
  __syncthreads();

  // phase 3 MFMA: out3[16 rows x 16 cols] per wave; rows by rg, col tile by cg (cols 20..31 zero)
  f32x4 acc3 = (f32x4){0.f, 0.f, 0.f, 0.f};
  #pragma unroll
  for (int kf = 0; kf < 4; ++kf) {
    bfrag ab = *(const bfrag*)&Ab[16 * rg + cl][kf * 32 + g4 * 8];
    bfrag vbh = *(const bfrag*)(gwf + ((size_t)(kf * 2 + cg) * 64 + l) * 8);
    acc3 = __builtin_amdgcn_mfma_f32_16x16x32_bf16(ab, vbh, acc3, 0, 0, 0);
  }
  int col = cg * 16 + cl;
  if (col < Cc) {
    #pragma unroll
    for (int j = 0; j < 4; ++j) {
      int row = r0 + 16 * rg + 4 * g4 + j;
      xwdh[(size_t)row * 32 + col] = __float2half_rn(acc3[j] * dis[row]);
    }
  }
}

// ---------------- GCN output ----------------
__global__ __launch_bounds__(256) void gcn_out_k(const __half* __restrict__ xwdh,
                                                 const int* __restrict__ row_ptr,
                                                 const uint2* __restrict__ cole,
                                                 const float* __restrict__ dis,
                                                 const float* __restrict__ bias,
                                                 float* __restrict__ out) {
  int node = blockIdx.x * 4 + (threadIdx.x >> 6);
  int lane = threadIdx.x & 63;
  int grp = lane / Cc, c = lane % Cc;       // grp 0..2 active, 3 = idle tail lanes
  float dv = dis[node];
  float acc = 0.f;
  int beg = row_ptr[node], end = row_ptr[node + 1];
  if (grp < 3) {
    for (int j = beg + grp; j < end; j += 3) {
      uint2 ce = cole[j];
      acc += __uint_as_float(ce.y) * __half2float(xwdh[(size_t)ce.x * 32 + c]);
    }
  }
  int l20 = lane + 20 < 64 ? lane + 20 : lane;
  int l40 = lane + 40 < 64 ? lane + 40 : lane;
  float tot = acc + __shfl(acc, l20) + __shfl(acc, l40);
  float val = 0.f;
  if (lane < Cc)
    val = dv * tot + dv * __half2float(xwdh[(size_t)node * 32 + c]) + bias[c];
  float red = (lane < Cc) ? val : -INFINITY;
  #pragma unroll
  for (int m = 32; m >= 1; m >>= 1) red = fmaxf(red, __shfl_xor(red, m));
  float ex = (lane < Cc) ? __expf(val - red) : 0.f;
  #pragma unroll
  for (int m = 32; m >= 1; m >>= 1) ex += __shfl_xor(ex, m);
  float ls = __logf(ex);
  if (lane < Cc) out[(size_t)node * Cc + c] = val - red - ls;
}

// ---------------- host ----------------
extern "C" void kernel_launch(void* const* d_in, const int* in_sizes, int n_in,
                              void* d_out, int out_size, void* d_ws, size_t ws_size,
                              hipStream_t stream) {
  const int*   x_ids = (const int*)d_in[0];
  const int*   ei    = (const int*)d_in[1];
  const int*   srcp  = ei;
  const int*   dstp  = ei + Ee;
  const float* eattr = (const float*)d_in[2];
  const float* emb   = (const float*)d_in[3];
  const float* ln_g  = (const float*)d_in[4];
  const float* ln_b  = (const float*)d_in[5];
  const float* tpar  = (const float*)d_in[6];
  const float* w1    = (const float*)d_in[7];
  const float* b1    = (const float*)d_in[8];
  const float* mg    = (const float*)d_in[9];
  const float* mb    = (const float*)d_in[10];
  const float* w2    = (const float*)d_in[11];
  const float* b2    = (const float*)d_in[12];
  const float* gw    = (const float*)d_in[13];
  const float* gb    = (const float*)d_in[14];
  float* out = (float*)d_out;

  char* ws = (char*)d_ws;
  float* h    = (float*)ws;  ws += (size_t)Nn * Fd * 4;
  __half* xnh = (__half*)ws; ws += (size_t)Nn * Fd * 2;
  __half* xwdh = (__half*)ws; ws += (size_t)Nn * 32 * 2;
  float* dis  = (float*)ws;  ws += (size_t)Nn * 4;
  unsigned short* h2b = (unsigned short*)ws; ws += (size_t)Nn * Fd * 2;
  unsigned short* w1h = (unsigned short*)ws; ws += (size_t)3 * Fd * Hid * 2;
  unsigned short* w2h = (unsigned short*)ws; ws += (size_t)3 * Fd * Hid * 2;
  unsigned short* gwf = (unsigned short*)ws; ws += (size_t)4096 * 2;
  int* row_ptr = (int*)ws; ws += (size_t)(Nn + 16) * 4;
  int* cnt   = (int*)ws;   ws += (size_t)Nn * 4;        // counts
  int* rank  = (int*)ws;   ws += (size_t)Ee * 4;        // per-edge rank
  uint2* cole = (uint2*)ws; ws += (size_t)Ee * 8;
  int* bsum  = (int*)ws;   ws += 256 * 4;
  if ((size_t)(ws - (char*)d_ws) > ws_size) return;  // workspace too small

  constexpr int NB = (Nn + 255) / 256;  // 157

  prep_w_k<<<(3 * Fd * Hid + 255) / 256, 256, 0, stream>>>(w1, w2, gw, w1h, w2h, gwf);

  // CSR by destination (rebuilt every call; deterministic positions via rank)
  zero_int_k<<<NB, 256, 0, stream>>>(cnt, Nn);
  count_k<<<2500, 256, 0, stream>>>(dstp, cnt, rank);
  blocksum_k<<<NB, 256, 0, stream>>>(cnt, bsum, Nn);
  scanbsum_k<<<1, 256, 0, stream>>>(bsum, NB);
  scanfinal_k<<<NB, 256, 0, stream>>>(cnt, bsum, row_ptr, Nn);
  scatter_k<<<2500, 256, 0, stream>>>(srcp, dstp, eattr, row_ptr, rank, cole);
  deg_dis_k<<<NB, 256, 0, stream>>>(row_ptr, cole, dis);

  embed_ln_k<<<Nn / 4, 256, 0, stream>>>(x_ids, emb, ln_g, ln_b, h, xnh);

  for (int i = 0; i < 3; ++i) {
    gen_agg_k<<<Nn / 16, 256, 0, stream>>>(xnh, row_ptr, cole, tpar + i, h2b);
    if (i < 2) {
      mlp0_k<<<Nn / 32, 256, 0, stream>>>(h2b,
          w1h + (size_t)i * Fd * Hid,
          b1 + i * Hid, mg + i * Hid, mb + i * Hid,
          w2h + (size_t)i * Fd * Hid, b2 + i * Fd, h,
          ln_g + (i + 1) * Fd, ln_b + (i + 1) * Fd, xnh);
    } else {
      mlp2_k<<<Nn / 32, 256, 0, stream>>>(h2b,
          w1h + (size_t)i * Fd * Hid,
          b1 + i * Hid, mg + i * Hid, mb + i * Hid,
          w2h + (size_t)i * Fd * Hid, b2 + i * Fd, h,
          gwf, dis, xwdh);
    }
  }

  gcn_out_k<<<Nn / 4, 256, 0, stream>>>(xwdh, row_ptr, cole, dis, gb, out);
}

// Round 26
// 256.072 us; speedup vs baseline: 1.1470x; 1.0011x over previous
//
#include <hip/hip_runtime.h>
#include <hip/hip_fp16.h>
#include <math.h>

// Problem constants (fixed by the reference)
constexpr int Nn  = 40000;
constexpr int Ee  = 640000;
constexpr int Fd  = 128;
constexpr int Hid = 256;
constexpr int Cc  = 20;
constexpr float GEN_EPS = 1e-7f;
constexpr float LN_EPS  = 1e-5f;

using bfrag = __attribute__((ext_vector_type(8))) short;   // 8 bf16 (4 VGPR)
using f32x4 = __attribute__((ext_vector_type(4))) float;   // 4 fp32 acc
typedef __attribute__((ext_vector_type(4))) unsigned short us4;

__device__ __forceinline__ unsigned short f2bf(float f) {
  unsigned u = __float_as_uint(f);
  u += 0x7FFF + ((u >> 16) & 1);          // RNE
  return (unsigned short)(u >> 16);
}

// ---------------- CSR build ----------------
__global__ void zero_int_k(int* __restrict__ p, int n) {
  int i = blockIdx.x * 256 + threadIdx.x;
  if (i < n) p[i] = 0;
}

// counts + per-edge rank (stable position within its dst segment)
__global__ void count_k(const int* __restrict__ dst, int* __restrict__ cnt,
                        int* __restrict__ rank) {
  int e = blockIdx.x * 256 + threadIdx.x;
  if (e < Ee) rank[e] = atomicAdd(&cnt[dst[e]], 1);
}

__device__ __forceinline__ int block_incl_scan256(int v) {
  int t = threadIdx.x, lane = t & 63, wid = t >> 6;
  int x = v;
  #pragma unroll
  for (int off = 1; off < 64; off <<= 1) {
    int y = __shfl_up(x, off);
    if (lane >= off) x += y;
  }
  __shared__ int wsum[4];
  if (lane == 63) wsum[wid] = x;
  __syncthreads();
  int add = 0;
  #pragma unroll
  for (int w = 0; w < 4; ++w) if (w < wid) add += wsum[w];
  return x + add;
}

__global__ __launch_bounds__(256) void blocksum_k(const int* __restrict__ cnt,
                                                  int* __restrict__ bsum, int n) {
  int i = blockIdx.x * 256 + threadIdx.x;
  int v = (i < n) ? cnt[i] : 0;
  int lane = threadIdx.x & 63, wid = threadIdx.x >> 6;
  #pragma unroll
  for (int m = 32; m >= 1; m >>= 1) v += __shfl_xor(v, m);
  __shared__ int s4[4];
  if (lane == 0) s4[wid] = v;
  __syncthreads();
  if (threadIdx.x == 0) bsum[blockIdx.x] = s4[0] + s4[1] + s4[2] + s4[3];
}

__global__ __launch_bounds__(256) void scanbsum_k(int* __restrict__ bsum, int nb) {
  int t = threadIdx.x;
  int v = (t < nb) ? bsum[t] : 0;
  int incl = block_incl_scan256(v);
  if (t < nb) bsum[t] = incl - v;   // exclusive
}

__global__ __launch_bounds__(256) void scanfinal_k(const int* __restrict__ cnt,
                                                   const int* __restrict__ bsum,
                                                   int* __restrict__ row_ptr, int n) {
  int b = blockIdx.x, t = threadIdx.x;
  int i = b * 256 + t;
  int v = (i < n) ? cnt[i] : 0;
  int incl = block_incl_scan256(v);
  if (i < n) row_ptr[i + 1] = bsum[b] + incl;
  if (b == 0 && t == 0) row_ptr[0] = 0;
}

// atomic-free scatter: position = row_ptr[dst] + precomputed rank
__global__ void scatter_k(const int* __restrict__ src, const int* __restrict__ dst,
                          const float* __restrict__ eattr,
                          const int* __restrict__ row_ptr, const int* __restrict__ rank,
                          uint2* __restrict__ cole) {
  int e = blockIdx.x * 256 + threadIdx.x;
  if (e >= Ee) return;
  int d = dst[e];
  int p = row_ptr[d] + rank[e];
  cole[p] = make_uint2((unsigned)src[e], __float_as_uint(eattr[e]));
}

// ---------------- weight prep: fp32 -> MFMA-fragment-ordered bf16 ----------------
// also emits gwf: gw[128][20] -> bf16 fragments padded to N=32 (cols 20..31 zero)
__global__ void prep_w_k(const float* __restrict__ w1, const float* __restrict__ w2,
                         const float* __restrict__ gw,
                         unsigned short* __restrict__ w1h, unsigned short* __restrict__ w2h,
                         unsigned short* __restrict__ gwf) {
  int i = blockIdx.x * 256 + threadIdx.x;
  constexpr int TOT = 3 * Fd * Hid;   // 98304
  if (i >= TOT) return;
  int j = i & 7, l = (i >> 3) & 63, tk = (i >> 9) & 63, layer = i >> 15;
  int k_lo = (l >> 4) * 4 + (j & 3) + 16 * (j >> 2);
  {
    int kc = tk >> 4, tt = tk & 15;          // w1: K=128 (kc<4), N=256 (tt<16)
    int k = kc * 32 + k_lo, c = tt * 16 + (l & 15);
    w1h[i] = f2bf(w1[((size_t)layer * Fd + k) * Hid + c]);
  }
  {
    int kc = tk >> 3, tt = tk & 7;           // w2: K=256 (kc<8), N=128 (tt<8)
    int k = kc * 32 + k_lo, c = tt * 16 + (l & 15);
    w2h[i] = f2bf(w2[((size_t)layer * Hid + k) * Fd + c]);
  }
  if (i < 4096) {                            // gwf: K=128 (kc<4), N=32 (tt<2)
    int tk2 = i >> 9;                        // 0..7
    int kc = tk2 >> 1, tt = tk2 & 1;
    int k = kc * 32 + k_lo, c = tt * 16 + (l & 15);
    gwf[i] = (c < Cc) ? f2bf(gw[(size_t)k * Cc + c]) : (unsigned short)0;
  }
}

// ---------------- fused embedding gather + layer-0 LN/ReLU + deg/dis ----------------
__global__ __launch_bounds__(256) void embed_ln_k(const int* __restrict__ ids,
                                                  const float* __restrict__ emb,
                                                  const float* __restrict__ g,
                                                  const float* __restrict__ b,
                                                  const int* __restrict__ row_ptr,
                                                  const uint2* __restrict__ cole,
                                                  __half* __restrict__ hh,
                                                  __half* __restrict__ xnh,
                                                  float* __restrict__ dis) {
  int node = blockIdx.x * 4 + (threadIdx.x >> 6);
  int lane = threadIdx.x & 63;
  float2 v = *(const float2*)(emb + (size_t)ids[node] * Fd + lane * 2);
  *(__half2*)(hh + (size_t)node * Fd + lane * 2) = __floats2half2_rn(v.x, v.y);
  float s = v.x + v.y;
  #pragma unroll
  for (int m = 32; m >= 1; m >>= 1) s += __shfl_xor(s, m);
  float mu = s * (1.f / 128.f);
  float d0 = v.x - mu, d1 = v.y - mu;
  float q = d0 * d0 + d1 * d1;
  #pragma unroll
  for (int m = 32; m >= 1; m >>= 1) q += __shfl_xor(q, m);
  float rs = rsqrtf(q * (1.f / 128.f) + LN_EPS);
  float2 gg = *(const float2*)(g + lane * 2);
  float2 bb = *(const float2*)(b + lane * 2);
  float ox = fmaxf(d0 * rs * gg.x + bb.x, 0.f);
  float oy = fmaxf(d1 * rs * gg.y + bb.y, 0.f);
  *(__half2*)(xnh + (size_t)node * Fd + lane * 2) = __floats2half2_rn(ox, oy);
  // deg (incl self loop) -> dis = rsqrt(deg), wave-parallel over edge segment
  int beg = row_ptr[node], end = row_ptr[node + 1];
  float sd = 0.f;
  for (int j = beg + lane; j < end; j += 64) sd += __uint_as_float(cole[j].y);
  #pragma unroll
  for (int m = 32; m >= 1; m >>= 1) sd += __shfl_xor(sd, m);
  if (lane == 0) dis[node] = rsqrtf(sd + 1.f);
}

// ---------------- GENConv aggregation: 4 nodes/wave, 8 features/lane -> bf16 h2 ----------------
__global__ __launch_bounds__(256) void gen_agg_k(const __half* __restrict__ xnh,
                                                 const int* __restrict__ row_ptr,
                                                 const uint2* __restrict__ cole,
                                                 const float* __restrict__ t_ptr,
                                                 unsigned short* __restrict__ h2b) {
  int wid = blockIdx.x * 4 + (threadIdx.x >> 6);
  int lane = threadIdx.x & 63;
  int sub = lane >> 4;
  int node = wid * 4 + sub;
  int f0 = (lane & 15) * 8;
  float t = t_ptr[0];
  int beg = row_ptr[node], end = row_ptr[node + 1];
  const __half* xb = xnh + f0;
  float se[8], sm[8];
  #pragma unroll
  for (int i = 0; i < 8; ++i) { se[i] = 0.f; sm[i] = 0.f; }

  for (int j = beg; j < end; j += 8) {
    int idx[8];
    #pragma unroll
    for (int k = 0; k < 8; ++k) idx[k] = (j + k < end) ? (int)cole[j + k].x : -1;
    uint4 hv[8];
    #pragma unroll
    for (int k = 0; k < 8; ++k)
      if (idx[k] >= 0) hv[k] = *(const uint4*)(xb + (size_t)idx[k] * Fd);
    #pragma unroll
    for (int k = 0; k < 8; ++k) {
      if (idx[k] >= 0) {
        const __half2* hp = (const __half2*)&hv[k];
        #pragma unroll
        for (int q = 0; q < 4; ++q) {
          float2 v = __half22float2(hp[q]);
          float m0 = v.x + GEN_EPS, m1 = v.y + GEN_EPS;
          float e0 = __expf(t * m0), e1 = __expf(t * m1);
          se[2 * q]     += e0;  se[2 * q + 1] += e1;
          sm[2 * q]      = fmaf(m0, e0, sm[2 * q]);
          sm[2 * q + 1]  = fmaf(m1, e1, sm[2 * q + 1]);
        }
      }
    }
  }

  // self/residual term from fp16 row; output bf16 (one 16B store)
  uint4 sv = *(const uint4*)(xb + (size_t)node * Fd);
  const __half2* sp2 = (const __half2*)&sv;
  unsigned short ob[8];
  #pragma unroll
  for (int q = 0; q < 4; ++q) {
    float2 sf = __half22float2(sp2[q]);
    ob[2 * q]     = f2bf(sf.x + sm[2 * q]     / (se[2 * q]     + 1e-16f));
    ob[2 * q + 1] = f2bf(sf.y + sm[2 * q + 1] / (se[2 * q + 1] + 1e-16f));
  }
  *(uint4*)(h2b + (size_t)node * Fd + f0) = *(uint4*)ob;
}

// ======== fused MLP core (phase 1: z = relu(LN(h2@W1+b1)) in LDS; phase 2: z@W2) ========
// 32-row tile, 4 waves: rg = row group (16 rows), cg = col group.
// Phase 1 N-split: 2 x 128 cols; phase 2 N-split: 2 x 64 cols.
__device__ __forceinline__ void mlp_core(const unsigned short* __restrict__ Az,
                                         const unsigned short* __restrict__ W1h,
                                         const float* __restrict__ b1,
                                         const float* __restrict__ g1,
                                         const float* __restrict__ bl1,
                                         const unsigned short* __restrict__ W2h,
                                         int r0,
                                         unsigned short (*Ab)[136],
                                         unsigned short (*Zl)[264],
                                         float (*sred)[32][2],
                                         f32x4* acc2) {
  const int t = threadIdx.x;
  const int w = t >> 6, l = t & 63;
  const int rg = w & 1, cg = w >> 1;
  const int g4 = l >> 4, cl = l & 15;

  // stage h2 (K=128 bf16) fragment-permuted
  {
    int row = t >> 3;
    int base = (t & 7) * 16;
    const unsigned short* sp = Az + (size_t)(r0 + row) * Fd + base;
    #pragma unroll
    for (int hb = 0; hb < 2; ++hb) {
      int kk0 = base + hb * 8;
      uint4 a = *(const uint4*)(sp + hb * 8);
      int chunk = kk0 >> 5, ww = kk0 & 31;
      int d = chunk * 32 + 8 * ((ww & 15) >> 2) + 4 * (ww >> 4);
      us4 v0 = {(unsigned short)a.x, (unsigned short)(a.x >> 16),
                (unsigned short)a.y, (unsigned short)(a.y >> 16)};
      us4 v1 = {(unsigned short)a.z, (unsigned short)(a.z >> 16),
                (unsigned short)a.w, (unsigned short)(a.w >> 16)};
      *(us4*)&Ab[row][d] = v0;
      *(us4*)&Ab[row][d + 8] = v1;
    }
  }
  __syncthreads();

  // phase 1 MFMA: 8 col tiles of this cg's 128 cols
  f32x4 acc[8];
  #pragma unroll
  for (int i = 0; i < 8; ++i) acc[i] = (f32x4){0.f, 0.f, 0.f, 0.f};
  for (int kc = 0; kc < 4; ++kc) {
    bfrag ab = *(const bfrag*)&Ab[16 * rg + cl][kc * 32 + g4 * 8];
    const unsigned short* bh = W1h + ((size_t)(kc * 16 + cg * 8) * 64 + l) * 8;
    #pragma unroll
    for (int tt = 0; tt < 8; ++tt) {
      bfrag vbh = *(const bfrag*)(bh + tt * 512);
      acc[tt] = __builtin_amdgcn_mfma_f32_16x16x32_bf16(ab, vbh, acc[tt], 0, 0, 0);
    }
  }

  // LN pass 1: +bias, per-row partial (s,q) over this wave's 128 cols
  float bcol[8], gcol[8], blc[8];
  #pragma unroll
  for (int tt = 0; tt < 8; ++tt) {
    int c = cg * 128 + 16 * tt + cl;
    bcol[tt] = b1[c]; gcol[tt] = g1[c]; blc[tt] = bl1[c];
  }
  #pragma unroll
  for (int j = 0; j < 4; ++j) {
    float s = 0.f, q = 0.f;
    #pragma unroll
    for (int tt = 0; tt < 8; ++tt) {
      float x = acc[tt][j] + bcol[tt];
      acc[tt][j] = x;
      s += x;
      q = fmaf(x, x, q);
    }
    #pragma unroll
    for (int m = 8; m >= 1; m >>= 1) { s += __shfl_xor(s, m); q += __shfl_xor(q, m); }
    if (cl == 0) {
      int rl = 16 * rg + 4 * g4 + j;
      sred[cg][rl][0] = s;
      sred[cg][rl][1] = q;
    }
  }
  __syncthreads();
  // LN pass 2: combine, normalize, relu, write z to LDS fragment-permuted
  #pragma unroll
  for (int j = 0; j < 4; ++j) {
    int rl = 16 * rg + 4 * g4 + j;
    float s = sred[0][rl][0] + sred[1][rl][0];
    float q = sred[0][rl][1] + sred[1][rl][1];
    float mu = s * (1.f / 256.f);
    float rs = rsqrtf(q * (1.f / 256.f) - mu * mu + LN_EPS);
    #pragma unroll
    for (int tt = 0; tt < 8; ++tt) {
      float z = fmaxf((acc[tt][j] - mu) * rs * gcol[tt] + blc[tt], 0.f);
      int d = (cl & 3) + 8 * (cl >> 2) + 4 * (tt & 1) + 32 * ((tt >> 1) + 4 * cg);
      Zl[rl][d] = f2bf(z);
    }
  }
  __syncthreads();                      // z tile complete (also fences sred reuse)

  // phase 2 MFMA: 4 col tiles of this cg's 64 cols, K=256 from Zl
  #pragma unroll
  for (int i = 0; i < 4; ++i) acc2[i] = (f32x4){0.f, 0.f, 0.f, 0.f};
  for (int kf = 0; kf < 8; ++kf) {
    bfrag ab = *(const bfrag*)&Zl[16 * rg + cl][kf * 32 + g4 * 8];
    const unsigned short* bh = W2h + ((size_t)(kf * 8 + cg * 4) * 64 + l) * 8;
    #pragma unroll
    for (int tt = 0; tt < 4; ++tt) {
      bfrag vbh = *(const bfrag*)(bh + tt * 512);
      acc2[tt] = __builtin_amdgcn_mfma_f32_16x16x32_bf16(ab, vbh, acc2[tt], 0, 0, 0);
    }
  }
}

// ---------------- fused MLP, layers 0/1: H += out + b2 (fp16); XNh = relu(LN(H)) ----------------
__global__ __launch_bounds__(256) void mlp0_k(const unsigned short* __restrict__ Az,
                                              const unsigned short* __restrict__ W1h,
                                              const float* __restrict__ b1,
                                              const float* __restrict__ g1,
                                              const float* __restrict__ bl1,
                                              const unsigned short* __restrict__ W2h,
                                              const float* __restrict__ b2,
                                              __half* __restrict__ H,
                                              const float* __restrict__ gN,
                                              const float* __restrict__ blN,
                                              __half* __restrict__ XNh) {
  __shared__ unsigned short Ab[32][136];
  __shared__ unsigned short Zl[32][264];
  __shared__ float sred[2][32][2];
  const int t = threadIdx.x;
  const int w = t >> 6, l = t & 63;
  const int rg = w & 1, cg = w >> 1;
  const int g4 = l >> 4, cl = l & 15;
  const int r0 = blockIdx.x * 32;

  f32x4 acc2[4];
  mlp_core(Az, W1h, b1, g1, bl1, W2h, r0, Ab, Zl, sred, acc2);

  float bcol[4], gcol[4], blc[4];
  #pragma unroll
  for (int tt = 0; tt < 4; ++tt) {
    int c = cg * 64 + 16 * tt + cl;
    bcol[tt] = b2[c];
    gcol[tt] = gN[c]; blc[tt] = blN[c];
  }
  // pass 1: residual + H write (fp16) + per-row partials over 64 cols
  #pragma unroll
  for (int j = 0; j < 4; ++j) {
    int row = r0 + 16 * rg + 4 * g4 + j;
    float s = 0.f, q = 0.f;
    #pragma unroll
    for (int tt = 0; tt < 4; ++tt) {
      size_t off = (size_t)row * Fd + cg * 64 + 16 * tt + cl;
      float hv = __half2float(H[off]) + acc2[tt][j] + bcol[tt];
      H[off] = __float2half_rn(hv);
      acc2[tt][j] = hv;
      s += hv;
      q = fmaf(hv, hv, q);
    }
    #pragma unroll
    for (int m = 8; m >= 1; m >>= 1) { s += __shfl_xor(s, m); q += __shfl_xor(q, m); }
    if (cl == 0) {
      int rl = 16 * rg + 4 * g4 + j;
      sred[cg][rl][0] = s;
      sred[cg][rl][1] = q;
    }
  }
  __syncthreads();
  // pass 2: combine, normalize, write fp16
  #pragma unroll
  for (int j = 0; j < 4; ++j) {
    int rl = 16 * rg + 4 * g4 + j;
    float s = sred[0][rl][0] + sred[1][rl][0];
    float q = sred[0][rl][1] + sred[1][rl][1];
    float mu = s * (1.f / 128.f);
    float rs = rsqrtf(q * (1.f / 128.f) - mu * mu + LN_EPS);
    int row = r0 + rl;
    #pragma unroll
    for (int tt = 0; tt < 4; ++tt) {
      float z = fmaxf((acc2[tt][j] - mu) * rs * gcol[tt] + blc[tt], 0.f);
      XNh[(size_t)row * Fd + cg * 64 + 16 * tt + cl] = __float2half_rn(z);
    }
  }
}

// ---------------- fused MLP, last layer: xwdh = fp16(dis*((H+out+b2)@gw)) via 3rd MFMA phase ----------------
__global__ __launch_bounds__(256) void mlp2_k(const unsigned short* __restrict__ Az,
                                              const unsigned short* __restrict__ W1h,
                                              const float* __restrict__ b1,
                                              const float* __restrict__ g1,
                                              const float* __restrict__ bl1,
                                              const unsigned short* __restrict__ W2h,
                                              const float* __restrict__ b2,
                                              const __half* __restrict__ H,
                                              const unsigned short* __restrict__ gwf,
                                              const float* __restrict__ dis,
                                              __half* __restrict__ xwdh) {
  __shared__ unsigned short Ab[32][136];
  __shared__ unsigned short Zl[32][264];
  __shared__ float sred[2][32][2];
  const int t = threadIdx.x;
  const int w = t >> 6, l = t & 63;
  const int rg = w & 1, cg = w >> 1;
  const int g4 = l >> 4, cl = l & 15;
  const int r0 = blockIdx.x * 32;

  f32x4 acc2[4];
  mlp_core(Az, W1h, b1, g1, bl1, W2h, r0, Ab, Zl, sred, acc2);

  float bcol[4];
  #pragma unroll
  for (int tt = 0; tt < 4; ++tt) bcol[tt] = b2[cg * 64 + 16 * tt + cl];

  // stage xfin = H + out + b2 into Ab as bf16, K=128 fragment-permuted
  // (Ab last read in phase 1; two barriers since -> safe to overwrite)
  #pragma unroll
  for (int j = 0; j < 4; ++j) {
    int rl = 16 * rg + 4 * g4 + j;
    #pragma unroll
    for (int tt = 0; tt < 4; ++tt) {
      int c = cg * 64 + 16 * tt + cl;
      size_t off = (size_t)(r0 + rl) * Fd + c;
      float xv = __half2float(H[off]) + acc2[tt][j] + bcol[tt];
      int d = 32 * (c >> 5) + 8 * ((c >> 2) & 3) + 4 * ((c >> 4) & 1) + (c & 3);
      Ab[rl][d] = f2bf(xv);
    }
  }
  __syncthreads();

  // phase 3 MFMA: out3[16 rows x 16 cols] per wave; rows by rg, col tile by cg (cols 20..31 zero)
  f32x4 acc3 = (f32x4){0.f, 0.f, 0.f, 0.f};
  #pragma unroll
  for (int kf = 0; kf < 4; ++kf) {
    bfrag ab = *(const bfrag*)&Ab[16 * rg + cl][kf * 32 + g4 * 8];
    bfrag vbh = *(const bfrag*)(gwf + ((size_t)(kf * 2 + cg) * 64 + l) * 8);
    acc3 = __builtin_amdgcn_mfma_f32_16x16x32_bf16(ab, vbh, acc3, 0, 0, 0);
  }
  int col = cg * 16 + cl;
  if (col < Cc) {
    #pragma unroll
    for (int j = 0; j < 4; ++j) {
      int row = r0 + 16 * rg + 4 * g4 + j;
      xwdh[(size_t)row * 32 + col] = __float2half_rn(acc3[j] * dis[row]);
    }
  }
}

// ---------------- GCN output ----------------
__global__ __launch_bounds__(256) void gcn_out_k(const __half* __restrict__ xwdh,
                                                 const int* __restrict__ row_ptr,
                                                 const uint2* __restrict__ cole,
                                                 const float* __restrict__ dis,
                                                 const float* __restrict__ bias,
                                                 float* __restrict__ out) {
  int node = blockIdx.x * 4 + (threadIdx.x >> 6);
  int lane = threadIdx.x & 63;
  int grp = lane / Cc, c = lane % Cc;       // grp 0..2 active, 3 = idle tail lanes
  float dv = dis[node];
  float acc = 0.f;
  int beg = row_ptr[node], end = row_ptr[node + 1];
  if (grp < 3) {
    for (int j = beg + grp; j < end; j += 3) {
      uint2 ce = cole[j];
      acc += __uint_as_float(ce.y) * __half2float(xwdh[(size_t)ce.x * 32 + c]);
    }
  }
  int l20 = lane + 20 < 64 ? lane + 20 : lane;
  int l40 = lane + 40 < 64 ? lane + 40 : lane;
  float tot = acc + __shfl(acc, l20) + __shfl(acc, l40);
  float val = 0.f;
  if (lane < Cc)
    val = dv * tot + dv * __half2float(xwdh[(size_t)node * 32 + c]) + bias[c];
  float red = (lane < Cc) ? val : -INFINITY;
  #pragma unroll
  for (int m = 32; m >= 1; m >>= 1) red = fmaxf(red, __shfl_xor(red, m));
  float ex = (lane < Cc) ? __expf(val - red) : 0.f;
  #pragma unroll
  for (int m = 32; m >= 1; m >>= 1) ex += __shfl_xor(ex, m);
  float ls = __logf(ex);
  if (lane < Cc) out[(size_t)node * Cc + c] = val - red - ls;
}

// ---------------- host ----------------
extern "C" void kernel_launch(void* const* d_in, const int* in_sizes, int n_in,
                              void* d_out, int out_size, void* d_ws, size_t ws_size,
                              hipStream_t stream) {
  const int*   x_ids = (const int*)d_in[0];
  const int*   ei    = (const int*)d_in[1];
  const int*   srcp  = ei;
  const int*   dstp  = ei + Ee;
  const float* eattr = (const float*)d_in[2];
  const float* emb   = (const float*)d_in[3];
  const float* ln_g  = (const float*)d_in[4];
  const float* ln_b  = (const float*)d_in[5];
  const float* tpar  = (const float*)d_in[6];
  const float* w1    = (const float*)d_in[7];
  const float* b1    = (const float*)d_in[8];
  const float* mg    = (const float*)d_in[9];
  const float* mb    = (const float*)d_in[10];
  const float* w2    = (const float*)d_in[11];
  const float* b2    = (const float*)d_in[12];
  const float* gw    = (const float*)d_in[13];
  const float* gb    = (const float*)d_in[14];
  float* out = (float*)d_out;

  char* ws = (char*)d_ws;
  __half* hh  = (__half*)ws; ws += (size_t)Nn * Fd * 2;
  __half* xnh = (__half*)ws; ws += (size_t)Nn * Fd * 2;
  __half* xwdh = (__half*)ws; ws += (size_t)Nn * 32 * 2;
  float* dis  = (float*)ws;  ws += (size_t)Nn * 4;
  unsigned short* h2b = (unsigned short*)ws; ws += (size_t)Nn * Fd * 2;
  unsigned short* w1h = (unsigned short*)ws; ws += (size_t)3 * Fd * Hid * 2;
  unsigned short* w2h = (unsigned short*)ws; ws += (size_t)3 * Fd * Hid * 2;
  unsigned short* gwf = (unsigned short*)ws; ws += (size_t)4096 * 2;
  int* row_ptr = (int*)ws; ws += (size_t)(Nn + 16) * 4;
  int* cnt   = (int*)ws;   ws += (size_t)Nn * 4;        // counts
  int* rank  = (int*)ws;   ws += (size_t)Ee * 4;        // per-edge rank
  uint2* cole = (uint2*)ws; ws += (size_t)Ee * 8;
  int* bsum  = (int*)ws;   ws += 256 * 4;
  if ((size_t)(ws - (char*)d_ws) > ws_size) return;  // workspace too small

  constexpr int NB = (Nn + 255) / 256;  // 157

  prep_w_k<<<(3 * Fd * Hid + 255) / 256, 256, 0, stream>>>(w1, w2, gw, w1h, w2h, gwf);

  // CSR by destination (rebuilt every call; deterministic positions via rank)
  zero_int_k<<<NB, 256, 0, stream>>>(cnt, Nn);
  count_k<<<2500, 256, 0, stream>>>(dstp, cnt, rank);
  blocksum_k<<<NB, 256, 0, stream>>>(cnt, bsum, Nn);
  scanbsum_k<<<1, 256, 0, stream>>>(bsum, NB);
  scanfinal_k<<<NB, 256, 0, stream>>>(cnt, bsum, row_ptr, Nn);
  scatter_k<<<2500, 256, 0, stream>>>(srcp, dstp, eattr, row_ptr, rank, cole);

  embed_ln_k<<<Nn / 4, 256, 0, stream>>>(x_ids, emb, ln_g, ln_b, row_ptr, cole,
                                         hh, xnh, dis);

  for (int i = 0; i < 3; ++i) {
    gen_agg_k<<<Nn / 16, 256, 0, stream>>>(xnh, row_ptr, cole, tpar + i, h2b);
    if (i < 2) {
      mlp0_k<<<Nn / 32, 256, 0, stream>>>(h2b,
          w1h + (size_t)i * Fd * Hid,
          b1 + i * Hid, mg + i * Hid, mb + i * Hid,
          w2h + (size_t)i * Fd * Hid, b2 + i * Fd, hh,
          ln_g + (i + 1) * Fd, ln_b + (i + 1) * Fd, xnh);
    } else {
      mlp2_k<<<Nn / 32, 256, 0, stream>>>(h2b,
          w1h + (size_t)i * Fd * Hid,
          b1 + i * Hid, mg + i * Hid, mb + i * Hid,
          w2h + (size_t)i * Fd * Hid, b2 + i * Fd, hh,
          gwf, dis, xwdh);
    }
  }

  gcn_out_k<<<Nn / 4, 256, 0, stream>>>(xwdh, row_ptr, cole, dis, gb, out);
}